// Round 1
// baseline (1072.697 us; speedup 1.0000x reference)
//
#include <hip/hip_runtime.h>
#include <math.h>

#define B_   2
#define L_   2048
#define D_   1024
#define H_   16
#define HD_  64
#define C_   128
#define N_   16
#define INV_SCALE 0.03125f   // 1/sqrt(1024)

// ---------------------------------------------------------------------------
// GEMM: C = A(MxK) * Bm(KxN) + bias. mode 0: scatter to Q/K/V head layout.
// mode 1: plain row-major write. 128x128 tile, BK=8, 256 threads, 8x8/thread.
// ---------------------------------------------------------------------------
__global__ __launch_bounds__(256) void gemm_kernel(
    const float* __restrict__ A, const float* __restrict__ Bm,
    const float* __restrict__ bias,
    float* __restrict__ Cq, float* __restrict__ Ck, float* __restrict__ Cv,
    float* __restrict__ Cplain, int Ncols, int Kdim, int mode)
{
  __shared__ __align__(16) float As[8][132];
  __shared__ __align__(16) float Bs[8][132];
  const int tid = threadIdx.x;
  const int tx = tid & 15, ty = tid >> 4;
  const int m0 = blockIdx.y * 128, n0 = blockIdx.x * 128;
  const int am = tid >> 1, ak = (tid & 1) * 4;
  const int bk = tid >> 5, bn = (tid & 31) * 4;
  const float* Aptr = A + (size_t)(m0 + am) * Kdim + ak;
  const float* Bptr = Bm + (size_t)bk * Ncols + n0 + bn;

  float acc[8][8];
  #pragma unroll
  for (int i = 0; i < 8; ++i)
    #pragma unroll
    for (int j = 0; j < 8; ++j) acc[i][j] = 0.f;

  float4 av = *(const float4*)(Aptr);
  float4 bv = *(const float4*)(Bptr);
  for (int kt = 0; kt < Kdim; kt += 8) {
    __syncthreads();
    As[ak+0][am] = av.x; As[ak+1][am] = av.y; As[ak+2][am] = av.z; As[ak+3][am] = av.w;
    *(float4*)&Bs[bk][bn] = bv;
    __syncthreads();
    if (kt + 8 < Kdim) {            // prefetch next tile during compute
      av = *(const float4*)(Aptr + kt + 8);
      bv = *(const float4*)(Bptr + (size_t)(kt + 8) * Ncols);
    }
    #pragma unroll
    for (int k = 0; k < 8; ++k) {
      float4 a0 = *(const float4*)&As[k][ty*8];
      float4 a1 = *(const float4*)&As[k][ty*8+4];
      float4 b0 = *(const float4*)&Bs[k][tx*8];
      float4 b1 = *(const float4*)&Bs[k][tx*8+4];
      float ar[8] = {a0.x,a0.y,a0.z,a0.w,a1.x,a1.y,a1.z,a1.w};
      float br[8] = {b0.x,b0.y,b0.z,b0.w,b1.x,b1.y,b1.z,b1.w};
      #pragma unroll
      for (int i = 0; i < 8; ++i)
        #pragma unroll
        for (int j = 0; j < 8; ++j)
          acc[i][j] = fmaf(ar[i], br[j], acc[i][j]);
    }
  }

  if (mode == 0) {
    #pragma unroll
    for (int j = 0; j < 8; ++j) {
      int gn = n0 + tx*8 + j;
      float bj = bias[gn];
      int which = gn >> 10, rem = gn & 1023;
      int h = rem >> 6, d = rem & 63;
      float* dst = (which == 0) ? Cq : (which == 1) ? Ck : Cv;
      #pragma unroll
      for (int i = 0; i < 8; ++i) {
        int gm = m0 + ty*8 + i;
        int b = gm >> 11, l = gm & 2047;
        dst[(((size_t)(b*H_ + h))*L_ + l)*HD_ + d] = acc[i][j] + bj;
      }
    }
  } else {
    #pragma unroll
    for (int i = 0; i < 8; ++i) {
      int gm = m0 + ty*8 + i;
      #pragma unroll
      for (int j = 0; j < 8; ++j) {
        int gn = n0 + tx*8 + j;
        Cplain[(size_t)gm * Ncols + gn] = acc[i][j] + bias[gn];
      }
    }
  }
}

// ---------------------------------------------------------------------------
// Per-chunk mean pools of Q,K and per-chunk V sums. grid BH*N blocks, 64 thr.
// ---------------------------------------------------------------------------
__global__ void pool_kernel(const float* __restrict__ Q, const float* __restrict__ K,
                            const float* __restrict__ V,
                            float* __restrict__ QP, float* __restrict__ KP,
                            float* __restrict__ VCS)
{
  int bh = blockIdx.x / N_, n = blockIdx.x % N_, d = threadIdx.x;
  size_t base = ((size_t)bh*L_ + n*C_)*HD_ + d;
  float qs = 0.f, ks = 0.f, vs = 0.f;
  for (int c = 0; c < C_; ++c) {
    qs += Q[base + (size_t)c*HD_];
    ks += K[base + (size_t)c*HD_];
    vs += V[base + (size_t)c*HD_];
  }
  size_t o = ((size_t)bh*N_ + n)*HD_ + d;
  QP[o] = qs * (1.f/128.f);
  KP[o] = ks * (1.f/128.f);
  VCS[o] = vs;
}

// Chunk-level suffix sums of V: CSUF[bh,n,d] = sum over chunks > n. 32 blk, 64 thr.
__global__ void csuf_kernel(const float* __restrict__ VCS, float* __restrict__ CSUF)
{
  int bh = blockIdx.x, d = threadIdx.x;
  float run = 0.f;
  for (int n = N_-1; n >= 0; --n) {
    size_t o = ((size_t)bh*N_ + n)*HD_ + d;
    CSUF[o] = run;
    run += VCS[o];
  }
}

// ---------------------------------------------------------------------------
// c2t[bh,n,c] = q_pool[bh,n,:] . K[bh, n*C+c, :]  + per-chunk max/min.
// grid BH*N blocks, 128 threads (one per c).
// ---------------------------------------------------------------------------
__global__ __launch_bounds__(128) void c2t_kernel(
    const float* __restrict__ QP, const float* __restrict__ K,
    float* __restrict__ C2T, float* __restrict__ C2TMX, float* __restrict__ C2TMN)
{
  __shared__ float qp_s[64];
  __shared__ float k_s[128*69];
  __shared__ float redmx[128];
  __shared__ float redmn[128];
  int bh = blockIdx.x / N_, n = blockIdx.x % N_, tid = threadIdx.x;
  if (tid < 64) qp_s[tid] = QP[((size_t)bh*N_ + n)*HD_ + tid];
  const float* src = K + ((size_t)bh*L_ + n*C_)*HD_;
  for (int i = 0; i < 64; ++i) {
    int flat = i*128 + tid;
    k_s[(flat>>6)*69 + (flat&63)] = src[flat];
  }
  __syncthreads();
  float s = 0.f;
  #pragma unroll 8
  for (int d = 0; d < 64; ++d) s = fmaf(qp_s[d], k_s[tid*69 + d], s);
  C2T[((size_t)bh*N_ + n)*C_ + tid] = s;
  redmx[tid] = s; redmn[tid] = s;
  __syncthreads();
  for (int st = 64; st > 0; st >>= 1) {
    if (tid < st) {
      redmx[tid] = fmaxf(redmx[tid], redmx[tid+st]);
      redmn[tid] = fminf(redmn[tid], redmn[tid+st]);
    }
    __syncthreads();
  }
  if (tid == 0) {
    C2TMX[bh*N_ + n] = redmx[0];
    C2TMN[bh*N_ + n] = redmn[0];
  }
}

// ---------------------------------------------------------------------------
// t2c[bh,l,n] = Q[bh,l,:] . k_pool[bh,n,:].  grid (BH, L/128), 256 threads.
// ---------------------------------------------------------------------------
__global__ __launch_bounds__(256) void t2c_kernel(
    const float* __restrict__ Q, const float* __restrict__ KP,
    float* __restrict__ T2C)
{
  __shared__ float kp_s[16*68];
  __shared__ float q_s[16*68];
  int bh = blockIdx.x, lt = blockIdx.y, tid = threadIdx.x;
  for (int i = tid; i < 1024; i += 256)
    kp_s[(i>>6)*68 + (i&63)] = KP[((size_t)bh*N_)*HD_ + i];
  int li = tid >> 4, n = tid & 15;
  for (int sub = 0; sub < 8; ++sub) {
    int lbase = lt*128 + sub*16;
    __syncthreads();
    for (int i = tid; i < 1024; i += 256)
      q_s[(i>>6)*68 + (i&63)] = Q[((size_t)bh*L_ + lbase)*HD_ + i];
    __syncthreads();
    float s = 0.f;
    #pragma unroll 8
    for (int d = 0; d < 64; ++d) s = fmaf(q_s[li*68 + d], kp_s[n*68 + d], s);
    T2C[((size_t)bh*L_ + lbase + li)*N_ + n] = s;
  }
}

// ---------------------------------------------------------------------------
// Attention: 64 q-rows per block (one (bh, qtile)), online softmax over
// chunks, half-chunk (64 keys) LDS staging. 4 waves x 16 rows; lane = head dim
// in accumulate role, lane = (row, c-stripe) in score role.
// Masked (j>l) entries contribute exp(0): closed-form via suffix V sums.
// ---------------------------------------------------------------------------
__global__ __launch_bounds__(256) void attn_kernel(
    const float* __restrict__ Q, const float* __restrict__ Kg,
    const float* __restrict__ Vg,
    const float* __restrict__ T2C, const float* __restrict__ C2T,
    const float* __restrict__ C2TMX, const float* __restrict__ C2TMN,
    const float* __restrict__ CSUF, float* __restrict__ AO)
{
  __shared__ __align__(16) float v_lds[64*68];
  __shared__ __align__(16) float p_lds[4*1024];
  __shared__ float c2t_lds[128];
  __shared__ float alpha_lds[64];
  __shared__ float e0_lds[64];
  __shared__ float den_lds[64];

  const int tid = threadIdx.x;
  const int w = tid >> 6;
  const int lane = tid & 63;
  const int r = lane & 15;        // score-role row within wave
  const int cg = lane >> 4;       // score-role c-stripe base
  const int qt = blockIdx.x;
  const int bh = blockIdx.y;
  const int l0 = qt * 64;
  const int nq = l0 >> 7;         // diagonal chunk index
  const int off = l0 & 127;       // 0 or 64: tile offset inside chunk
  const int myrow = l0 + w*16 + r;
  const int pc = off + w*16 + r;  // row position inside diag chunk
  const size_t bhL = (size_t)bh * L_;

  float m = -1e30f, den = 0.f;
  float acc[16], sv[16];
  #pragma unroll
  for (int i = 0; i < 16; ++i) { acc[i] = 0.f; sv[i] = 0.f; }

  float* pw = p_lds + w*1024;

  for (int n = 0; n <= nq; ++n) {
    const bool diag = (n == nq);
    float mx = 0.f, mn = 0.f, tval = 0.f;
    if (!diag) {
      mx = C2TMX[bh*N_ + n];
      mn = C2TMN[bh*N_ + n];
      tval = T2C[(bhL + myrow)*N_ + n] * INV_SCALE;
    }
    for (int hf = 0; hf < 2; ++hf) {
      const int cbase = hf * 64;
      __syncthreads();  // previous accumulate done; safe to restage
      {
        const float* src = (diag ? Kg : Vg) + (bhL + n*C_ + cbase)*HD_;
        #pragma unroll
        for (int i2 = 0; i2 < 4; ++i2) {
          int flat = i2*1024 + tid*4;
          int c = flat >> 6, d = flat & 63;
          *(float4*)&v_lds[c*68 + d] = *(const float4*)(src + flat);
        }
        if (!diag && hf == 0 && tid < 128)
          c2t_lds[tid] = C2T[((size_t)bh*N_ + n)*C_ + tid];
      }
      __syncthreads();

      // ---------------- score phase ----------------
      float alpha, csum = 0.f;
      if (!diag) {
        float cmax = fmaxf(tval*mx, tval*mn);   // analytic chunk max
        float mnew = fmaxf(m, cmax);
        alpha = __expf(m - mnew);
        m = mnew;
        #pragma unroll 4
        for (int j = 0; j < 16; ++j) {
          int cl = cg + 4*j;
          float p = __expf(tval * c2t_lds[cbase + cl] - mnew);
          pw[lane + 64*j] = p;                  // = p[c_local][r], stride-1
          csum += p;
        }
      } else {
        float qreg[64];
        const float* qrow = Q + (bhL + myrow)*HD_;
        #pragma unroll
        for (int d4 = 0; d4 < 16; ++d4) {
          float4 qv = *(const float4*)(qrow + d4*4);
          qreg[4*d4+0] = qv.x; qreg[4*d4+1] = qv.y;
          qreg[4*d4+2] = qv.z; qreg[4*d4+3] = qv.w;
        }
        float lmax = -1e30f;
        #pragma unroll 2
        for (int j = 0; j < 16; ++j) {
          int cl = cg + 4*j;
          float d0=0.f, d1=0.f, d2=0.f, d3=0.f;
          #pragma unroll
          for (int d4 = 0; d4 < 16; ++d4) {
            float4 kv = *(const float4*)&v_lds[cl*68 + d4*4];
            d0 = fmaf(qreg[4*d4+0], kv.x, d0);
            d1 = fmaf(qreg[4*d4+1], kv.y, d1);
            d2 = fmaf(qreg[4*d4+2], kv.z, d2);
            d3 = fmaf(qreg[4*d4+3], kv.w, d3);
          }
          float sc = ((cbase + cl) <= pc) ? (d0+d1+d2+d3) * INV_SCALE : -1e30f;
          pw[lane + 64*j] = sc;                 // park raw score
          lmax = fmaxf(lmax, sc);
        }
        lmax = fmaxf(lmax, __shfl_xor(lmax, 16));
        lmax = fmaxf(lmax, __shfl_xor(lmax, 32));
        float mnew = fmaxf(m, lmax);
        alpha = __expf(m - mnew);
        m = mnew;
        #pragma unroll 4
        for (int j = 0; j < 16; ++j) {
          float sc2 = pw[lane + 64*j];
          float p = (sc2 > -1e29f) ? __expf(sc2 - mnew) : 0.f;
          pw[lane + 64*j] = p;
          csum += p;
        }
      }
      csum += __shfl_xor(csum, 16);
      csum += __shfl_xor(csum, 32);
      den = den * alpha + csum;
      if (cg == 0) alpha_lds[w*16 + r] = alpha;

      if (diag) {  // swap K half -> V half
        __syncthreads();
        const float* src = Vg + (bhL + n*C_ + cbase)*HD_;
        #pragma unroll
        for (int i2 = 0; i2 < 4; ++i2) {
          int flat = i2*1024 + tid*4;
          int c = flat >> 6, d = flat & 63;
          *(float4*)&v_lds[c*68 + d] = *(const float4*)(src + flat);
        }
      }
      __syncthreads();

      // ---------------- accumulate phase (lane = head dim) ----------------
      #pragma unroll
      for (int i = 0; i < 16; ++i) acc[i] *= alpha_lds[w*16 + i];
      #pragma unroll 2
      for (int c = 0; c < 64; ++c) {
        float vv = v_lds[c*68 + lane];
        const float* pp = pw + c*16;
        float4 p0 = *(const float4*)(pp);
        float4 p1 = *(const float4*)(pp + 4);
        float4 p2 = *(const float4*)(pp + 8);
        float4 p3 = *(const float4*)(pp + 12);
        acc[0]  = fmaf(p0.x, vv, acc[0]);   acc[1]  = fmaf(p0.y, vv, acc[1]);
        acc[2]  = fmaf(p0.z, vv, acc[2]);   acc[3]  = fmaf(p0.w, vv, acc[3]);
        acc[4]  = fmaf(p1.x, vv, acc[4]);   acc[5]  = fmaf(p1.y, vv, acc[5]);
        acc[6]  = fmaf(p1.z, vv, acc[6]);   acc[7]  = fmaf(p1.w, vv, acc[7]);
        acc[8]  = fmaf(p2.x, vv, acc[8]);   acc[9]  = fmaf(p2.y, vv, acc[9]);
        acc[10] = fmaf(p2.z, vv, acc[10]);  acc[11] = fmaf(p2.w, vv, acc[11]);
        acc[12] = fmaf(p3.x, vv, acc[12]);  acc[13] = fmaf(p3.y, vv, acc[13]);
        acc[14] = fmaf(p3.z, vv, acc[14]);  acc[15] = fmaf(p3.w, vv, acc[15]);
      }
      if (diag) {  // within-chunk suffix V sums (masked-zero numerator part)
        #pragma unroll
        for (int i = 0; i < 16; ++i) {
          int pcr = off + w*16 + i;
          int lo = pcr + 1 - cbase;
          if (lo < 0) lo = 0;
          for (int c = lo; c < 64; ++c) sv[i] += v_lds[c*68 + lane];
        }
      }
    }
  }

  // -------- masked-zero (score=0) suffix contribution --------
  {
    int cnt = (L_ - 1) - myrow;
    float mnew = (cnt > 0) ? fmaxf(m, 0.f) : m;
    float alpha = __expf(m - mnew);
    float e0 = (cnt > 0) ? __expf(-mnew) : 0.f;
    den = den * alpha + e0 * (float)cnt;
    if (cg == 0) {
      alpha_lds[w*16 + r] = alpha;
      e0_lds[w*16 + r] = e0;
      den_lds[w*16 + r] = den;
    }
  }
  __syncthreads();
  {
    const int b = bh >> 4, h = bh & 15;
    const float csufv = CSUF[((size_t)bh*N_ + nq)*HD_ + lane];
    #pragma unroll
    for (int i = 0; i < 16; ++i) {
      int row = l0 + w*16 + i;
      float suffix = sv[i] + csufv;
      float o = (acc[i] * alpha_lds[w*16 + i] + e0_lds[w*16 + i] * suffix)
                / den_lds[w*16 + i];
      AO[((size_t)b*L_ + row)*D_ + h*HD_ + lane] = o;
    }
  }
}

// ---------------------------------------------------------------------------
extern "C" void kernel_launch(void* const* d_in, const int* in_sizes, int n_in,
                              void* d_out, int out_size, void* d_ws, size_t ws_size,
                              hipStream_t stream)
{
  (void)in_sizes; (void)n_in; (void)out_size; (void)ws_size;
  const float* x      = (const float*)d_in[0];
  const float* w_qkv  = (const float*)d_in[1];
  const float* b_qkv  = (const float*)d_in[2];
  const float* w_o    = (const float*)d_in[3];
  const float* b_o    = (const float*)d_in[4];
  float* out = (float*)d_out;

  float* ws = (float*)d_ws;
  float* Qb    = ws;                    // (BH, L, HD)  4,194,304
  float* Kb    = Qb + 4194304;
  float* Vb    = Kb + 4194304;
  float* QP    = Vb + 4194304;          // (BH, N, HD)  32768
  float* KP    = QP + 32768;
  float* VCS   = KP + 32768;
  float* CSUF  = VCS + 32768;
  float* T2C   = CSUF + 32768;          // (BH, L, N)   1,048,576
  float* C2T   = T2C + 1048576;         // (BH, N, C)   65536
  float* C2TMX = C2T + 65536;           // (BH, N)      512
  float* C2TMN = C2TMX + 512;
  float* AO    = C2TMN + 512;           // (B, L, D)    4,194,304

  // 1) QKV projection: (4096x1024)@(1024x3072)+b -> Q,K,V head layout
  gemm_kernel<<<dim3(24, 32), 256, 0, stream>>>(
      x, w_qkv, b_qkv, Qb, Kb, Vb, nullptr, 3*D_, D_, 0);
  // 2) chunk pools + chunk V sums
  pool_kernel<<<B_*H_*N_, 64, 0, stream>>>(Qb, Kb, Vb, QP, KP, VCS);
  // 3) chunk-level suffix sums of V
  csuf_kernel<<<B_*H_, 64, 0, stream>>>(VCS, CSUF);
  // 4) chunk2token factors + per-chunk max/min
  c2t_kernel<<<B_*H_*N_, 128, 0, stream>>>(QP, Kb, C2T, C2TMX, C2TMN);
  // 5) token2chunk factors
  t2c_kernel<<<dim3(B_*H_, L_/128), 256, 0, stream>>>(Qb, KP, T2C);
  // 6) fused chunked attention with online softmax
  attn_kernel<<<dim3(L_/64, B_*H_), 256, 0, stream>>>(
      Qb, Kb, Vb, T2C, C2T, C2TMX, C2TMN, CSUF, AO);
  // 7) output projection: (4096x1024)@(1024x1024)+b
  gemm_kernel<<<dim3(8, 32), 256, 0, stream>>>(
      AO, w_o, b_o, nullptr, nullptr, nullptr, out, D_, D_, 1);
}

// Round 2
// 277.069 us; speedup vs baseline: 3.8716x; 3.8716x over previous
//
#include <hip/hip_runtime.h>
#include <math.h>

#define B_   2
#define L_   2048
#define D_   1024
#define H_   16
#define HD_  64
#define C_   128
#define N_   16
#define INV_SCALE 0.03125f   // 1/sqrt(1024)

typedef _Float16 h8 __attribute__((ext_vector_type(8)));
typedef _Float16 h4 __attribute__((ext_vector_type(4)));
typedef float    f4 __attribute__((ext_vector_type(4)));

#define MFMA16(a, b, c) __builtin_amdgcn_mfma_f32_16x16x32_f16((a), (b), (c), 0, 0, 0)

// ---------------------------------------------------------------------------
// x fp32 -> fp16 flat
// ---------------------------------------------------------------------------
__global__ __launch_bounds__(256) void cvtx_kernel(const float* __restrict__ X,
                                                   _Float16* __restrict__ Xh)
{
  int i = (blockIdx.x * 256 + threadIdx.x) * 4;
  float4 v = *(const float4*)(X + i);
  h4 o = { (_Float16)v.x, (_Float16)v.y, (_Float16)v.z, (_Float16)v.w };
  *(h4*)(Xh + i) = o;
}

// ---------------------------------------------------------------------------
// W (Kd x Nc, fp32) -> WT (Nc x Kd, fp16) tiled transpose
// ---------------------------------------------------------------------------
__global__ __launch_bounds__(256) void wt_kernel(const float* __restrict__ W,
                                                 _Float16* __restrict__ WT,
                                                 int Nc, int Kd)
{
  __shared__ float ts[32][36];
  const int tid = threadIdx.x;
  const int n0 = blockIdx.x * 32, k0 = blockIdx.y * 32;
  {
    int kr = tid >> 3, nc4 = (tid & 7) * 4;
    float4 v = *(const float4*)&W[(size_t)(k0 + kr) * Nc + n0 + nc4];
    ts[kr][nc4+0] = v.x; ts[kr][nc4+1] = v.y; ts[kr][nc4+2] = v.z; ts[kr][nc4+3] = v.w;
  }
  __syncthreads();
  {
    int nr = tid >> 3, kc4 = (tid & 7) * 4;
    h4 o = { (_Float16)ts[kc4+0][nr], (_Float16)ts[kc4+1][nr],
             (_Float16)ts[kc4+2][nr], (_Float16)ts[kc4+3][nr] };
    *(h4*)&WT[(size_t)(n0 + nr) * Kd + k0 + kc4] = o;
  }
}

// ---------------------------------------------------------------------------
// fp16 MFMA GEMM: C = A(M x Kd) * Bt^T + bias.  A row-major fp16 (k contig),
// Bt = B^T (Nc x Kd) fp16 (k contig). 128x128 tile, BK=32, 4 waves (2x2).
// mode 0: scatter epilogue -> Qh/Kh fp16 + Vf fp32 head layout.
// mode 1: plain fp32 row-major (Ncols=1024).
// ---------------------------------------------------------------------------
__global__ __launch_bounds__(256) void gemm16_kernel(
    const _Float16* __restrict__ A, const _Float16* __restrict__ Bt,
    const float* __restrict__ bias,
    _Float16* __restrict__ Qh, _Float16* __restrict__ Kh, float* __restrict__ Vf,
    float* __restrict__ out, int Kd, int mode)
{
  __shared__ __align__(16) _Float16 As[128 * 40];
  __shared__ __align__(16) _Float16 Bs[128 * 40];
  const int tid = threadIdx.x;
  const int lane = tid & 63, w = tid >> 6;
  const int wm = w >> 1, wn = w & 1;
  const int q = lane >> 4, r = lane & 15;
  const int m0 = blockIdx.y * 128, n0 = blockIdx.x * 128;
  const int sr = tid >> 1, scc = (tid & 1) * 16;
  const _Float16* Ag = A + (size_t)(m0 + sr) * Kd + scc;
  const _Float16* Bg = Bt + (size_t)(n0 + sr) * Kd + scc;

  f4 acc[4][4];
  #pragma unroll
  for (int s = 0; s < 4; ++s)
    #pragma unroll
    for (int t = 0; t < 4; ++t) acc[s][t] = (f4){0.f, 0.f, 0.f, 0.f};

  int4 apre0 = *(const int4*)Ag;
  int4 apre1 = *(const int4*)(Ag + 8);
  int4 bpre0 = *(const int4*)Bg;
  int4 bpre1 = *(const int4*)(Bg + 8);

  for (int kt = 0; kt < Kd; kt += 32) {
    __syncthreads();
    *(int4*)&As[sr * 40 + scc]     = apre0;
    *(int4*)&As[sr * 40 + scc + 8] = apre1;
    *(int4*)&Bs[sr * 40 + scc]     = bpre0;
    *(int4*)&Bs[sr * 40 + scc + 8] = bpre1;
    __syncthreads();
    if (kt + 32 < Kd) {
      apre0 = *(const int4*)(Ag + kt + 32);
      apre1 = *(const int4*)(Ag + kt + 40);
      bpre0 = *(const int4*)(Bg + kt + 32);
      bpre1 = *(const int4*)(Bg + kt + 40);
    }
    h8 af[4], bf[4];
    #pragma unroll
    for (int s = 0; s < 4; ++s)
      af[s] = *(const h8*)&As[(wm * 64 + s * 16 + r) * 40 + q * 8];
    #pragma unroll
    for (int t = 0; t < 4; ++t)
      bf[t] = *(const h8*)&Bs[(wn * 64 + t * 16 + r) * 40 + q * 8];
    #pragma unroll
    for (int s = 0; s < 4; ++s)
      #pragma unroll
      for (int t = 0; t < 4; ++t)
        acc[s][t] = MFMA16(af[s], bf[t], acc[s][t]);
  }

  if (mode == 0) {
    #pragma unroll
    for (int t = 0; t < 4; ++t) {
      int gn = n0 + wn * 64 + t * 16 + r;
      float bj = bias[gn];
      int which = gn >> 10, rem = gn & 1023;
      int h2 = rem >> 6, d2 = rem & 63;
      #pragma unroll
      for (int s = 0; s < 4; ++s) {
        #pragma unroll
        for (int i = 0; i < 4; ++i) {
          int gm = m0 + wm * 64 + s * 16 + q * 4 + i;
          int b2 = gm >> 11, l2 = gm & 2047;
          float val = acc[s][t][i] + bj;
          size_t idx = (((size_t)(b2 * H_ + h2)) * L_ + l2) * HD_ + d2;
          if (which == 0)      Qh[idx] = (_Float16)val;
          else if (which == 1) Kh[idx] = (_Float16)val;
          else                 Vf[idx] = val;
        }
      }
    }
  } else {
    #pragma unroll
    for (int t = 0; t < 4; ++t) {
      int gn = n0 + wn * 64 + t * 16 + r;
      float bj = bias[gn];
      #pragma unroll
      for (int s = 0; s < 4; ++s)
        #pragma unroll
        for (int i = 0; i < 4; ++i) {
          int gm = m0 + wm * 64 + s * 16 + q * 4 + i;
          out[(size_t)gm * 1024 + gn] = acc[s][t][i] + bj;
        }
    }
  }
}

// ---------------------------------------------------------------------------
// Chunk mean pools of Q,K (fp16 in, fp32 out). grid BH*N, 64 thr.
// ---------------------------------------------------------------------------
__global__ void pool_kernel(const _Float16* __restrict__ Qh,
                            const _Float16* __restrict__ Kh,
                            float* __restrict__ QP, float* __restrict__ KP)
{
  int bh = blockIdx.x >> 4, n = blockIdx.x & 15, d = threadIdx.x;
  size_t base = ((size_t)bh * L_ + n * C_) * HD_ + d;
  float qs = 0.f, ks = 0.f;
  #pragma unroll 8
  for (int c = 0; c < C_; ++c) {
    qs += (float)Qh[base + (size_t)c * HD_];
    ks += (float)Kh[base + (size_t)c * HD_];
  }
  size_t o = ((size_t)bh * N_ + n) * HD_ + d;
  QP[o] = qs * (1.f / 128.f);
  KP[o] = ks * (1.f / 128.f);
}

// ---------------------------------------------------------------------------
// Per-position within-chunk suffix V sums (SUF2) + chunk totals (VCS).
// grid BH*N, 256 thr (64 d x 4 quarter-chunks).
// ---------------------------------------------------------------------------
__global__ __launch_bounds__(256) void suf_kernel(const float* __restrict__ Vf,
                                                  float* __restrict__ SUF2,
                                                  float* __restrict__ VCS)
{
  __shared__ float qs[4][64];
  int bh = blockIdx.x >> 4, n = blockIdx.x & 15;
  int d = threadIdx.x & 63, q2 = threadIdx.x >> 6;
  size_t base = ((size_t)bh * L_ + n * C_ + q2 * 32) * HD_ + d;
  float v[32];
  #pragma unroll
  for (int j = 0; j < 32; ++j) v[j] = Vf[base + (size_t)j * HD_];
  float s = 0.f;
  #pragma unroll
  for (int j = 0; j < 32; ++j) s += v[j];
  qs[q2][d] = s;
  __syncthreads();
  float run = 0.f;
  for (int t2 = q2 + 1; t2 < 4; ++t2) run += qs[t2][d];
  #pragma unroll
  for (int j = 31; j >= 0; --j) {
    SUF2[base + (size_t)j * HD_] = run;
    run += v[j];
  }
  if (q2 == 0)
    VCS[((size_t)bh * N_ + n) * HD_ + d] = qs[0][d] + qs[1][d] + qs[2][d] + qs[3][d];
}

// Chunk-level suffix sums. 32 blk, 64 thr.
__global__ void csuf_kernel(const float* __restrict__ VCS, float* __restrict__ CSUF)
{
  int bh = blockIdx.x, d = threadIdx.x;
  float run = 0.f;
  for (int n = N_ - 1; n >= 0; --n) {
    size_t o = ((size_t)bh * N_ + n) * HD_ + d;
    CSUF[o] = run;
    run += VCS[o];
  }
}

// ---------------------------------------------------------------------------
// V transpose: Vf[bh][l][d] fp32 -> VT[bh][d][l] fp16. block per (ltile, bh).
// ---------------------------------------------------------------------------
__global__ __launch_bounds__(256) void vt_kernel(const float* __restrict__ Vf,
                                                 _Float16* __restrict__ VT)
{
  __shared__ _Float16 t_s[64 * 136];
  const int tid = threadIdx.x;
  const int bh = blockIdx.y, l0 = blockIdx.x * 128;
  {
    int l = tid >> 1, d0 = (tid & 1) * 32;
    const float* src = Vf + ((size_t)bh * L_ + l0 + l) * HD_ + d0;
    #pragma unroll
    for (int j = 0; j < 8; ++j) {
      float4 vv = *(const float4*)(src + j * 4);
      t_s[(d0 + j*4 + 0) * 136 + l] = (_Float16)vv.x;
      t_s[(d0 + j*4 + 1) * 136 + l] = (_Float16)vv.y;
      t_s[(d0 + j*4 + 2) * 136 + l] = (_Float16)vv.z;
      t_s[(d0 + j*4 + 3) * 136 + l] = (_Float16)vv.w;
    }
  }
  __syncthreads();
  {
    int d = tid >> 2, lc = (tid & 3) * 32;
    _Float16* dst = VT + ((size_t)bh * HD_ + d) * L_ + l0 + lc;
    #pragma unroll
    for (int j = 0; j < 4; ++j)
      *(int4*)(dst + j * 8) = *(const int4*)&t_s[d * 136 + lc + j * 8];
  }
}

// ---------------------------------------------------------------------------
// c2t[bh,n,c] = q_pool . K[c] + per-chunk max/min. grid BH*N, 128 thr.
// ---------------------------------------------------------------------------
__global__ __launch_bounds__(128) void c2t_kernel(
    const float* __restrict__ QP, const _Float16* __restrict__ Kh,
    float* __restrict__ C2T, float* __restrict__ C2TMX, float* __restrict__ C2TMN)
{
  __shared__ float qp_s[64];
  __shared__ float k_s[128 * 69];
  __shared__ float redmx[128];
  __shared__ float redmn[128];
  int bh = blockIdx.x >> 4, n = blockIdx.x & 15, tid = threadIdx.x;
  if (tid < 64) qp_s[tid] = QP[((size_t)bh * N_ + n) * HD_ + tid];
  size_t base = ((size_t)bh * L_ + n * C_) * HD_;
  for (int i = 0; i < 64; ++i) {
    int flat = i * 128 + tid;
    k_s[(flat >> 6) * 69 + (flat & 63)] = (float)Kh[base + flat];
  }
  __syncthreads();
  float s = 0.f;
  #pragma unroll 8
  for (int d = 0; d < 64; ++d) s = fmaf(qp_s[d], k_s[tid * 69 + d], s);
  C2T[((size_t)bh * N_ + n) * C_ + tid] = s;
  redmx[tid] = s; redmn[tid] = s;
  __syncthreads();
  for (int st = 64; st > 0; st >>= 1) {
    if (tid < st) {
      redmx[tid] = fmaxf(redmx[tid], redmx[tid + st]);
      redmn[tid] = fminf(redmn[tid], redmn[tid + st]);
    }
    __syncthreads();
  }
  if (tid == 0) {
    C2TMX[bh * N_ + n] = redmx[0];
    C2TMN[bh * N_ + n] = redmn[0];
  }
}

// ---------------------------------------------------------------------------
// t2c[bh,l,n] = Q[l] . k_pool[n]. grid (BH, L/128), 256 thr.
// ---------------------------------------------------------------------------
__global__ __launch_bounds__(256) void t2c_kernel(
    const _Float16* __restrict__ Qh, const float* __restrict__ KP,
    float* __restrict__ T2C)
{
  __shared__ float kp_s[16 * 68];
  __shared__ float q_s[16 * 68];
  int bh = blockIdx.x, lt = blockIdx.y, tid = threadIdx.x;
  for (int i = tid; i < 1024; i += 256)
    kp_s[(i >> 6) * 68 + (i & 63)] = KP[((size_t)bh * N_) * HD_ + i];
  int li = tid >> 4, n = tid & 15;
  for (int sub = 0; sub < 8; ++sub) {
    int lbase = lt * 128 + sub * 16;
    __syncthreads();
    for (int i = tid; i < 1024; i += 256)
      q_s[(i >> 6) * 68 + (i & 63)] = (float)Qh[((size_t)bh * L_ + lbase) * HD_ + i];
    __syncthreads();
    float s = 0.f;
    #pragma unroll 8
    for (int d = 0; d < 64; ++d) s = fmaf(q_s[li * 68 + d], kp_s[n * 68 + d], s);
    T2C[((size_t)bh * L_ + lbase + li) * N_ + n] = s;
  }
}

// ---------------------------------------------------------------------------
// MFMA attention. Block = (bh, 64 q-rows), 4 waves x 16 rows.
// Off-diag: rank-1 P built in registers in A-frag layout -> MFMA with VT tile.
// Diag: QK^T MFMA, mask/exp in C-layout, P via LDS round-trip -> PV MFMA.
// Masked (j>row) entries contribute exp(0): closed form via SUF2/CSUF.
// ---------------------------------------------------------------------------
__global__ __launch_bounds__(256) void attn2_kernel(
    const _Float16* __restrict__ Qh, const _Float16* __restrict__ Kh,
    const _Float16* __restrict__ VT,
    const float* __restrict__ T2C, const float* __restrict__ C2T,
    const float* __restrict__ C2TMX, const float* __restrict__ C2TMN,
    const float* __restrict__ CSUF, const float* __restrict__ SUF2,
    _Float16* __restrict__ AOh)
{
  __shared__ __align__(16) _Float16 kv_s[128 * 72];   // Ks[c][d]@72 or Vs[d][c]@136
  __shared__ __align__(16) _Float16 p_s[4 * 16 * 136];
  __shared__ float c2t_s[128];

  const int tid = threadIdx.x;
  const int w = tid >> 6, lane = tid & 63;
  const int q = lane >> 4, r = lane & 15;
  const int qt = blockIdx.x, bh = blockIdx.y;
  const int l0 = qt * 64;
  const int nq = l0 >> 7;
  const size_t bhL = (size_t)bh * L_;
  const int rowA = l0 + w * 16 + r;       // row whose softmax state this lane owns

  float m = -1e30f, den = 0.f;
  f4 oacc[4];
  #pragma unroll
  for (int t = 0; t < 4; ++t) oacc[t] = (f4){0.f, 0.f, 0.f, 0.f};

  _Float16* pw = p_s + w * 2176;

  for (int n = 0; n <= nq; ++n) {
    if (n < nq) {
      // ---------------- off-diagonal rank-1 chunk ----------------
      __syncthreads();
      {
        int d = tid >> 2, c8 = (tid & 3) * 8;
        const _Float16* src = VT + ((size_t)bh * HD_ + d) * L_ + n * C_ + c8;
        #pragma unroll
        for (int jj = 0; jj < 4; ++jj)
          *(int4*)&kv_s[d * 136 + c8 + jj * 32] = *(const int4*)(src + jj * 32);
        if (tid < 128) c2t_s[tid] = C2T[((size_t)bh * N_ + n) * C_ + tid];
      }
      __syncthreads();
      float tval = T2C[(bhL + rowA) * N_ + n] * INV_SCALE;
      float mxv = C2TMX[bh * N_ + n], mnv = C2TMN[bh * N_ + n];
      float cmax = fmaxf(tval * mxv, tval * mnv);
      float mnew = fmaxf(m, cmax);
      float alpha = __expf(m - mnew);
      m = mnew;
      float al0 = __shfl(alpha, (q << 2) + 0);
      float al1 = __shfl(alpha, (q << 2) + 1);
      float al2 = __shfl(alpha, (q << 2) + 2);
      float al3 = __shfl(alpha, (q << 2) + 3);
      #pragma unroll
      for (int t = 0; t < 4; ++t) {
        oacc[t][0] *= al0; oacc[t][1] *= al1;
        oacc[t][2] *= al2; oacc[t][3] *= al3;
      }
      float csum = 0.f;
      #pragma unroll
      for (int s = 0; s < 4; ++s) {
        const float* cp = &c2t_s[s * 32 + q * 8];
        float4 ca = *(const float4*)cp;
        float4 cb = *(const float4*)(cp + 4);
        float p0 = __expf(tval * ca.x - mnew), p1 = __expf(tval * ca.y - mnew);
        float p2 = __expf(tval * ca.z - mnew), p3 = __expf(tval * ca.w - mnew);
        float p4 = __expf(tval * cb.x - mnew), p5 = __expf(tval * cb.y - mnew);
        float p6 = __expf(tval * cb.z - mnew), p7 = __expf(tval * cb.w - mnew);
        csum += p0 + p1 + p2 + p3 + p4 + p5 + p6 + p7;
        h8 pa = { (_Float16)p0, (_Float16)p1, (_Float16)p2, (_Float16)p3,
                  (_Float16)p4, (_Float16)p5, (_Float16)p6, (_Float16)p7 };
        #pragma unroll
        for (int t = 0; t < 4; ++t) {
          h8 vb = *(const h8*)&kv_s[(t * 16 + r) * 136 + s * 32 + q * 8];
          oacc[t] = MFMA16(pa, vb, oacc[t]);
        }
      }
      csum += __shfl_xor(csum, 16);
      csum += __shfl_xor(csum, 32);
      den = den * alpha + csum;
    } else {
      // ---------------- diagonal chunk: direct QK^T ----------------
      __syncthreads();
      {
        int c = tid >> 1, dc = (tid & 1) * 32;
        const _Float16* src = Kh + (bhL + n * C_ + c) * HD_ + dc;
        #pragma unroll
        for (int jj = 0; jj < 4; ++jj)
          *(int4*)&kv_s[c * 72 + dc + jj * 8] = *(const int4*)(src + jj * 8);
      }
      __syncthreads();
      f4 sc[8];
      #pragma unroll
      for (int u = 0; u < 8; ++u) sc[u] = (f4){0.f, 0.f, 0.f, 0.f};
      #pragma unroll
      for (int s2 = 0; s2 < 2; ++s2) {
        h8 qa = *(const h8*)(Qh + (bhL + rowA) * HD_ + s2 * 32 + q * 8);
        #pragma unroll
        for (int u = 0; u < 8; ++u) {
          h8 kb = *(const h8*)&kv_s[(u * 16 + r) * 72 + s2 * 32 + q * 8];
          sc[u] = MFMA16(qa, kb, sc[u]);
        }
      }
      float rm[4] = {-1e30f, -1e30f, -1e30f, -1e30f};
      #pragma unroll
      for (int u = 0; u < 8; ++u) {
        int col = n * C_ + u * 16 + r;
        #pragma unroll
        for (int i = 0; i < 4; ++i) {
          int row = l0 + w * 16 + q * 4 + i;
          float v = sc[u][i] * INV_SCALE;
          v = (col <= row) ? v : -1e30f;
          sc[u][i] = v;
          rm[i] = fmaxf(rm[i], v);
        }
      }
      #pragma unroll
      for (int i = 0; i < 4; ++i) {
        rm[i] = fmaxf(rm[i], __shfl_xor(rm[i], 1));
        rm[i] = fmaxf(rm[i], __shfl_xor(rm[i], 2));
        rm[i] = fmaxf(rm[i], __shfl_xor(rm[i], 4));
        rm[i] = fmaxf(rm[i], __shfl_xor(rm[i], 8));
      }
      int srcl = (r >> 2) << 4;
      int ri = r & 3;
      float t0 = __shfl(rm[0], srcl), t1 = __shfl(rm[1], srcl);
      float t2 = __shfl(rm[2], srcl), t3 = __shfl(rm[3], srcl);
      float myrm = ri == 0 ? t0 : ri == 1 ? t1 : ri == 2 ? t2 : t3;
      float mnew = fmaxf(m, myrm);
      float alpha = __expf(m - mnew);
      m = mnew;
      float mrow[4], al[4];
      #pragma unroll
      for (int i = 0; i < 4; ++i) {
        mrow[i] = __shfl(mnew, (q << 2) + i);
        al[i]   = __shfl(alpha, (q << 2) + i);
      }
      float cs[4] = {0.f, 0.f, 0.f, 0.f};
      #pragma unroll
      for (int u = 0; u < 8; ++u)
        #pragma unroll
        for (int i = 0; i < 4; ++i) {
          float v = sc[u][i];
          float p = (v > -1e29f) ? __expf(v - mrow[i]) : 0.f;
          cs[i] += p;
          pw[(q * 4 + i) * 136 + u * 16 + r] = (_Float16)p;
        }
      #pragma unroll
      for (int i = 0; i < 4; ++i) {
        cs[i] += __shfl_xor(cs[i], 1);
        cs[i] += __shfl_xor(cs[i], 2);
        cs[i] += __shfl_xor(cs[i], 4);
        cs[i] += __shfl_xor(cs[i], 8);
      }
      float c0 = __shfl(cs[0], srcl), c1 = __shfl(cs[1], srcl);
      float c2 = __shfl(cs[2], srcl), c3 = __shfl(cs[3], srcl);
      float mycs = ri == 0 ? c0 : ri == 1 ? c1 : ri == 2 ? c2 : c3;
      den = den * alpha + mycs;
      #pragma unroll
      for (int t = 0; t < 4; ++t) {
        oacc[t][0] *= al[0]; oacc[t][1] *= al[1];
        oacc[t][2] *= al[2]; oacc[t][3] *= al[3];
      }
      // restage V over K tile
      __syncthreads();
      {
        int d = tid >> 2, c8 = (tid & 3) * 8;
        const _Float16* src = VT + ((size_t)bh * HD_ + d) * L_ + n * C_ + c8;
        #pragma unroll
        for (int jj = 0; jj < 4; ++jj)
          *(int4*)&kv_s[d * 136 + c8 + jj * 32] = *(const int4*)(src + jj * 32);
      }
      __syncthreads();
      #pragma unroll
      for (int s = 0; s < 4; ++s) {
        h8 pa = *(const h8*)&pw[r * 136 + s * 32 + q * 8];
        #pragma unroll
        for (int t = 0; t < 4; ++t) {
          h8 vb = *(const h8*)&kv_s[(t * 16 + r) * 136 + s * 32 + q * 8];
          oacc[t] = MFMA16(pa, vb, oacc[t]);
        }
      }
    }
  }

  // -------- masked-zero (score=0) closed-form contribution + output --------
  int cnt = (L_ - 1) - rowA;
  float mfin = (cnt > 0) ? fmaxf(m, 0.f) : m;
  float alphaf = __expf(m - mfin);
  float e0 = (cnt > 0) ? __expf(-mfin) : 0.f;
  den = den * alphaf + e0 * (float)cnt;
  float alf[4], e0r[4], dnr[4];
  #pragma unroll
  for (int i = 0; i < 4; ++i) {
    alf[i] = __shfl(alphaf, (q << 2) + i);
    e0r[i] = __shfl(e0,     (q << 2) + i);
    dnr[i] = __shfl(den,    (q << 2) + i);
  }
  const int b2 = bh >> 4, h2 = bh & 15;
  #pragma unroll
  for (int t = 0; t < 4; ++t) {
    int d = t * 16 + r;
    float csf = CSUF[((size_t)bh * N_ + nq) * HD_ + d];
    #pragma unroll
    for (int i = 0; i < 4; ++i) {
      int row = l0 + w * 16 + q * 4 + i;
      float suf = SUF2[(bhL + row) * HD_ + d] + csf;
      float o = (oacc[t][i] * alf[i] + e0r[i] * suf) / dnr[i];
      AOh[((size_t)b2 * L_ + row) * D_ + h2 * HD_ + d] = (_Float16)o;
    }
  }
}

// ---------------------------------------------------------------------------
extern "C" void kernel_launch(void* const* d_in, const int* in_sizes, int n_in,
                              void* d_out, int out_size, void* d_ws, size_t ws_size,
                              hipStream_t stream)
{
  (void)in_sizes; (void)n_in; (void)out_size; (void)ws_size;
  const float* x     = (const float*)d_in[0];
  const float* w_qkv = (const float*)d_in[1];
  const float* b_qkv = (const float*)d_in[2];
  const float* w_o   = (const float*)d_in[3];
  const float* b_o   = (const float*)d_in[4];
  float* out = (float*)d_out;

  char* p = (char*)d_ws;
  _Float16* xh   = (_Float16*)p; p += (size_t)4194304 * 2;
  _Float16* wqT  = (_Float16*)p; p += (size_t)3145728 * 2;
  _Float16* woT  = (_Float16*)p; p += (size_t)1048576 * 2;
  _Float16* Qh   = (_Float16*)p; p += (size_t)4194304 * 2;
  _Float16* Kh   = (_Float16*)p; p += (size_t)4194304 * 2;
  float*    Vf   = (float*)p;    p += (size_t)4194304 * 4;
  _Float16* VT   = (_Float16*)p; p += (size_t)4194304 * 2;
  _Float16* AOh  = (_Float16*)p; p += (size_t)4194304 * 2;
  float*    SUF2 = (float*)p;    p += (size_t)4194304 * 4;
  float*    T2C  = (float*)p;    p += (size_t)1048576 * 4;
  float*    C2T  = (float*)p;    p += (size_t)65536 * 4;
  float*    QP   = (float*)p;    p += (size_t)32768 * 4;
  float*    KP   = (float*)p;    p += (size_t)32768 * 4;
  float*    VCS  = (float*)p;    p += (size_t)32768 * 4;
  float*    CSUF = (float*)p;    p += (size_t)32768 * 4;
  float*    MXa  = (float*)p;    p += (size_t)512 * 4;
  float*    MNa  = (float*)p;    p += (size_t)512 * 4;

  cvtx_kernel<<<4096, 256, 0, stream>>>(x, xh);
  wt_kernel<<<dim3(96, 32), 256, 0, stream>>>(w_qkv, wqT, 3 * D_, D_);
  wt_kernel<<<dim3(32, 32), 256, 0, stream>>>(w_o, woT, D_, D_);
  gemm16_kernel<<<dim3(24, 32), 256, 0, stream>>>(
      xh, wqT, b_qkv, Qh, Kh, Vf, nullptr, D_, 0);
  pool_kernel<<<B_ * H_ * N_, 64, 0, stream>>>(Qh, Kh, QP, KP);
  suf_kernel<<<B_ * H_ * N_, 256, 0, stream>>>(Vf, SUF2, VCS);
  csuf_kernel<<<B_ * H_, 64, 0, stream>>>(VCS, CSUF);
  vt_kernel<<<dim3(L_ / 128, B_ * H_), 256, 0, stream>>>(Vf, VT);
  c2t_kernel<<<B_ * H_ * N_, 128, 0, stream>>>(QP, Kh, C2T, MXa, MNa);
  t2c_kernel<<<dim3(B_ * H_, L_ / 128), 256, 0, stream>>>(Qh, KP, T2C);
  attn2_kernel<<<dim3(L_ / 64, B_ * H_), 256, 0, stream>>>(
      Qh, Kh, VT, T2C, C2T, MXa, MNa, CSUF, SUF2, AOh);
  gemm16_kernel<<<dim3(8, 32), 256, 0, stream>>>(
      AOh, woT, b_o, nullptr, nullptr, nullptr, out, D_, 1);
}

// Round 3
// 256.754 us; speedup vs baseline: 4.1779x; 1.0791x over previous
//
#include <hip/hip_runtime.h>
#include <math.h>

#define B_   2
#define L_   2048
#define D_   1024
#define H_   16
#define HD_  64
#define C_   128
#define N_   16
#define INV_SCALE 0.03125f   // 1/sqrt(1024)

typedef _Float16 h8 __attribute__((ext_vector_type(8)));
typedef _Float16 h4 __attribute__((ext_vector_type(4)));
typedef float    f4 __attribute__((ext_vector_type(4)));

#define MFMA16(a, b, c) __builtin_amdgcn_mfma_f32_16x16x32_f16((a), (b), (c), 0, 0, 0)

__device__ __forceinline__ void gl_lds16(const _Float16* g, _Float16* l) {
  __builtin_amdgcn_global_load_lds(
      (const __attribute__((address_space(1))) void*)g,
      (__attribute__((address_space(3))) void*)l, 16, 0, 0);
}

// ---------------------------------------------------------------------------
// x fp32 -> fp16 flat
// ---------------------------------------------------------------------------
__global__ __launch_bounds__(256) void cvtx_kernel(const float* __restrict__ X,
                                                   _Float16* __restrict__ Xh)
{
  int i = (blockIdx.x * 256 + threadIdx.x) * 4;
  float4 v = *(const float4*)(X + i);
  h4 o = { (_Float16)v.x, (_Float16)v.y, (_Float16)v.z, (_Float16)v.w };
  *(h4*)(Xh + i) = o;
}

// ---------------------------------------------------------------------------
// W (Kd x Nc, fp32) -> WT (Nc x Kd, fp16) tiled transpose
// ---------------------------------------------------------------------------
__global__ __launch_bounds__(256) void wt_kernel(const float* __restrict__ W,
                                                 _Float16* __restrict__ WT,
                                                 int Nc, int Kd)
{
  __shared__ float ts[32][36];
  const int tid = threadIdx.x;
  const int n0 = blockIdx.x * 32, k0 = blockIdx.y * 32;
  {
    int kr = tid >> 3, nc4 = (tid & 7) * 4;
    float4 v = *(const float4*)&W[(size_t)(k0 + kr) * Nc + n0 + nc4];
    ts[kr][nc4+0] = v.x; ts[kr][nc4+1] = v.y; ts[kr][nc4+2] = v.z; ts[kr][nc4+3] = v.w;
  }
  __syncthreads();
  {
    int nr = tid >> 3, kc4 = (tid & 7) * 4;
    h4 o = { (_Float16)ts[kc4+0][nr], (_Float16)ts[kc4+1][nr],
             (_Float16)ts[kc4+2][nr], (_Float16)ts[kc4+3][nr] };
    *(h4*)&WT[(size_t)(n0 + nr) * Kd + k0 + kc4] = o;
  }
}

// ---------------------------------------------------------------------------
// fp16 MFMA GEMM with global_load_lds staging (m97-style).
// C = A(M x Kd) * Bt^T + bias. A, Bt row-major fp16 k-contiguous.
// 128x128 tile, BK=32, 4 waves (2x2 of 64x64). LDS layout: row-major
// stride 32 fp16, k-chunks (16B) XOR-swizzled by (row>>2)&3 via permuted
// per-lane SOURCE addresses (LDS dest of global_load_lds is lane*16 fixed).
// mode 0: scatter epilogue -> Qh/Kh fp16 + Vf fp32 head layout.
// mode 1: plain fp32 row-major (Ncols=1024).
// ---------------------------------------------------------------------------
__global__ __launch_bounds__(256) void gemm16_kernel(
    const _Float16* __restrict__ A, const _Float16* __restrict__ Bt,
    const float* __restrict__ bias,
    _Float16* __restrict__ Qh, _Float16* __restrict__ Kh, float* __restrict__ Vf,
    float* __restrict__ out, int Kd, int mode)
{
  __shared__ __align__(16) _Float16 As[4096];
  __shared__ __align__(16) _Float16 Bs[4096];
  const int tid = threadIdx.x;
  const int lane = tid & 63, w = tid >> 6;
  const int wm = w >> 1, wn = w & 1;
  const int q = lane >> 4, r = lane & 15;
  const int m0 = blockIdx.y * 128, n0 = blockIdx.x * 128;

  // staging: slot f = w*64 + lane (pass0), +256 (pass1); row = f>>2,
  // slot-chunk = f&3 holds data-chunk (f&3) ^ ((row>>2)&3)
  const int Rr = tid >> 2;                       // row, pass 0
  const int cd = (tid & 3) ^ ((Rr >> 2) & 3);    // swizzled source k-chunk
  const _Float16* Ag = A + (size_t)(m0 + Rr) * Kd + cd * 8;
  const _Float16* Bg = Bt + (size_t)(n0 + Rr) * Kd + cd * 8;
  const size_t rowStep = (size_t)64 * Kd;        // pass1: rows +64
  _Float16* Asl = As + w * 512;                  // wave-uniform LDS dest
  _Float16* Bsl = Bs + w * 512;

  f4 acc[4][4];
  #pragma unroll
  for (int s = 0; s < 4; ++s)
    #pragma unroll
    for (int t = 0; t < 4; ++t) acc[s][t] = (f4){0.f, 0.f, 0.f, 0.f};

  const int sw = (r >> 2) & 3;
  const int koff = ((q ^ sw) << 3);

  for (int kt = 0; kt < Kd; kt += 32) {
    __syncthreads();
    gl_lds16(Ag + kt, Asl);
    gl_lds16(Ag + kt + rowStep, Asl + 2048);
    gl_lds16(Bg + kt, Bsl);
    gl_lds16(Bg + kt + rowStep, Bsl + 2048);
    __syncthreads();
    h8 af[4], bf[4];
    #pragma unroll
    for (int s = 0; s < 4; ++s)
      af[s] = *(const h8*)&As[(wm * 64 + s * 16 + r) * 32 + koff];
    #pragma unroll
    for (int t = 0; t < 4; ++t)
      bf[t] = *(const h8*)&Bs[(wn * 64 + t * 16 + r) * 32 + koff];
    #pragma unroll
    for (int s = 0; s < 4; ++s)
      #pragma unroll
      for (int t = 0; t < 4; ++t)
        acc[s][t] = MFMA16(af[s], bf[t], acc[s][t]);
  }

  if (mode == 0) {
    #pragma unroll
    for (int t = 0; t < 4; ++t) {
      int gn = n0 + wn * 64 + t * 16 + r;
      float bj = bias[gn];
      int which = gn >> 10, rem = gn & 1023;
      int h2 = rem >> 6, d2 = rem & 63;
      #pragma unroll
      for (int s = 0; s < 4; ++s) {
        #pragma unroll
        for (int i = 0; i < 4; ++i) {
          int gm = m0 + wm * 64 + s * 16 + q * 4 + i;
          int b2 = gm >> 11, l2 = gm & 2047;
          float val = acc[s][t][i] + bj;
          size_t idx = (((size_t)(b2 * H_ + h2)) * L_ + l2) * HD_ + d2;
          if (which == 0)      Qh[idx] = (_Float16)val;
          else if (which == 1) Kh[idx] = (_Float16)val;
          else                 Vf[idx] = val;
        }
      }
    }
  } else {
    #pragma unroll
    for (int t = 0; t < 4; ++t) {
      int gn = n0 + wn * 64 + t * 16 + r;
      float bj = bias[gn];
      #pragma unroll
      for (int s = 0; s < 4; ++s)
        #pragma unroll
        for (int i = 0; i < 4; ++i) {
          int gm = m0 + wm * 64 + s * 16 + q * 4 + i;
          out[(size_t)gm * 1024 + gn] = acc[s][t][i] + bj;
        }
    }
  }
}

// ---------------------------------------------------------------------------
// Chunk mean pools of Q,K (fp16 in, fp32 out). grid BH*N, 64 thr.
// ---------------------------------------------------------------------------
__global__ void pool_kernel(const _Float16* __restrict__ Qh,
                            const _Float16* __restrict__ Kh,
                            float* __restrict__ QP, float* __restrict__ KP)
{
  int bh = blockIdx.x >> 4, n = blockIdx.x & 15, d = threadIdx.x;
  size_t base = ((size_t)bh * L_ + n * C_) * HD_ + d;
  float qs = 0.f, ks = 0.f;
  #pragma unroll 8
  for (int c = 0; c < C_; ++c) {
    qs += (float)Qh[base + (size_t)c * HD_];
    ks += (float)Kh[base + (size_t)c * HD_];
  }
  size_t o = ((size_t)bh * N_ + n) * HD_ + d;
  QP[o] = qs * (1.f / 128.f);
  KP[o] = ks * (1.f / 128.f);
}

// ---------------------------------------------------------------------------
// Per-position within-chunk suffix V sums (SUF2) + chunk totals (VCS).
// ---------------------------------------------------------------------------
__global__ __launch_bounds__(256) void suf_kernel(const float* __restrict__ Vf,
                                                  float* __restrict__ SUF2,
                                                  float* __restrict__ VCS)
{
  __shared__ float qs[4][64];
  int bh = blockIdx.x >> 4, n = blockIdx.x & 15;
  int d = threadIdx.x & 63, q2 = threadIdx.x >> 6;
  size_t base = ((size_t)bh * L_ + n * C_ + q2 * 32) * HD_ + d;
  float v[32];
  #pragma unroll
  for (int j = 0; j < 32; ++j) v[j] = Vf[base + (size_t)j * HD_];
  float s = 0.f;
  #pragma unroll
  for (int j = 0; j < 32; ++j) s += v[j];
  qs[q2][d] = s;
  __syncthreads();
  float run = 0.f;
  for (int t2 = q2 + 1; t2 < 4; ++t2) run += qs[t2][d];
  #pragma unroll
  for (int j = 31; j >= 0; --j) {
    SUF2[base + (size_t)j * HD_] = run;
    run += v[j];
  }
  if (q2 == 0)
    VCS[((size_t)bh * N_ + n) * HD_ + d] = qs[0][d] + qs[1][d] + qs[2][d] + qs[3][d];
}

// Chunk-level suffix sums. 32 blk, 64 thr.
__global__ void csuf_kernel(const float* __restrict__ VCS, float* __restrict__ CSUF)
{
  int bh = blockIdx.x, d = threadIdx.x;
  float run = 0.f;
  for (int n = N_ - 1; n >= 0; --n) {
    size_t o = ((size_t)bh * N_ + n) * HD_ + d;
    CSUF[o] = run;
    run += VCS[o];
  }
}

// ---------------------------------------------------------------------------
// V transpose: Vf[bh][l][d] fp32 -> VT[bh][d][l] fp16.
// ---------------------------------------------------------------------------
__global__ __launch_bounds__(256) void vt_kernel(const float* __restrict__ Vf,
                                                 _Float16* __restrict__ VT)
{
  __shared__ _Float16 t_s[64 * 136];
  const int tid = threadIdx.x;
  const int bh = blockIdx.y, l0 = blockIdx.x * 128;
  {
    int l = tid >> 1, d0 = (tid & 1) * 32;
    const float* src = Vf + ((size_t)bh * L_ + l0 + l) * HD_ + d0;
    #pragma unroll
    for (int j = 0; j < 8; ++j) {
      float4 vv = *(const float4*)(src + j * 4);
      t_s[(d0 + j*4 + 0) * 136 + l] = (_Float16)vv.x;
      t_s[(d0 + j*4 + 1) * 136 + l] = (_Float16)vv.y;
      t_s[(d0 + j*4 + 2) * 136 + l] = (_Float16)vv.z;
      t_s[(d0 + j*4 + 3) * 136 + l] = (_Float16)vv.w;
    }
  }
  __syncthreads();
  {
    int d = tid >> 2, lc = (tid & 3) * 32;
    _Float16* dst = VT + ((size_t)bh * HD_ + d) * L_ + l0 + lc;
    #pragma unroll
    for (int j = 0; j < 4; ++j)
      *(int4*)(dst + j * 8) = *(const int4*)&t_s[d * 136 + lc + j * 8];
  }
}

// ---------------------------------------------------------------------------
// c2t[bh,n,c] = q_pool . K[c] + per-chunk max/min. grid BH*N, 128 thr.
// ---------------------------------------------------------------------------
__global__ __launch_bounds__(128) void c2t_kernel(
    const float* __restrict__ QP, const _Float16* __restrict__ Kh,
    float* __restrict__ C2T, float* __restrict__ C2TMX, float* __restrict__ C2TMN)
{
  __shared__ float qp_s[64];
  __shared__ float k_s[128 * 69];
  __shared__ float redmx[128];
  __shared__ float redmn[128];
  int bh = blockIdx.x >> 4, n = blockIdx.x & 15, tid = threadIdx.x;
  if (tid < 64) qp_s[tid] = QP[((size_t)bh * N_ + n) * HD_ + tid];
  size_t base = ((size_t)bh * L_ + n * C_) * HD_;
  for (int i = 0; i < 64; ++i) {
    int flat = i * 128 + tid;
    k_s[(flat >> 6) * 69 + (flat & 63)] = (float)Kh[base + flat];
  }
  __syncthreads();
  float s = 0.f;
  #pragma unroll 8
  for (int d = 0; d < 64; ++d) s = fmaf(qp_s[d], k_s[tid * 69 + d], s);
  C2T[((size_t)bh * N_ + n) * C_ + tid] = s;
  redmx[tid] = s; redmn[tid] = s;
  __syncthreads();
  for (int st = 64; st > 0; st >>= 1) {
    if (tid < st) {
      redmx[tid] = fmaxf(redmx[tid], redmx[tid + st]);
      redmn[tid] = fminf(redmn[tid], redmn[tid + st]);
    }
    __syncthreads();
  }
  if (tid == 0) {
    C2TMX[bh * N_ + n] = redmx[0];
    C2TMN[bh * N_ + n] = redmn[0];
  }
}

// ---------------------------------------------------------------------------
// t2c[bh,l,n] = Q[l] . k_pool[n]. grid (BH, L/128), 256 thr.
// ---------------------------------------------------------------------------
__global__ __launch_bounds__(256) void t2c_kernel(
    const _Float16* __restrict__ Qh, const float* __restrict__ KP,
    float* __restrict__ T2C)
{
  __shared__ float kp_s[16 * 68];
  __shared__ float q_s[16 * 68];
  int bh = blockIdx.x, lt = blockIdx.y, tid = threadIdx.x;
  for (int i = tid; i < 1024; i += 256)
    kp_s[(i >> 6) * 68 + (i & 63)] = KP[((size_t)bh * N_) * HD_ + i];
  int li = tid >> 4, n = tid & 15;
  for (int sub = 0; sub < 8; ++sub) {
    int lbase = lt * 128 + sub * 16;
    __syncthreads();
    for (int i = tid; i < 1024; i += 256)
      q_s[(i >> 6) * 68 + (i & 63)] = (float)Qh[((size_t)bh * L_ + lbase) * HD_ + i];
    __syncthreads();
    float s = 0.f;
    #pragma unroll 8
    for (int d = 0; d < 64; ++d) s = fmaf(q_s[li * 68 + d], kp_s[n * 68 + d], s);
    T2C[((size_t)bh * L_ + lbase + li) * N_ + n] = s;
  }
}

// ---------------------------------------------------------------------------
// MFMA attention, LOAD-BALANCED: each block processes q-tiles qp and 31-qp
// (constant 17 chunk-iterations per block; 512 blocks = 2/CU, no tail).
// Block decode is XCD-aware: XCD j (id%8==j) owns bh in [4j, 4j+4) for L2
// locality of VT/Kh/Qh.
// ---------------------------------------------------------------------------
__global__ __launch_bounds__(256) void attn2_kernel(
    const _Float16* __restrict__ Qh, const _Float16* __restrict__ Kh,
    const _Float16* __restrict__ VT,
    const float* __restrict__ T2C, const float* __restrict__ C2T,
    const float* __restrict__ C2TMX, const float* __restrict__ C2TMN,
    const float* __restrict__ CSUF, const float* __restrict__ SUF2,
    _Float16* __restrict__ AOh)
{
  __shared__ __align__(16) _Float16 kv_s[128 * 72];   // Ks[c][d]@72 or Vs[d][c]@136
  __shared__ __align__(16) _Float16 p_s[4 * 16 * 136];
  __shared__ float c2t_s[128];

  const int tid = threadIdx.x;
  const int w = tid >> 6, lane = tid & 63;
  const int q = lane >> 4, r = lane & 15;
  const int id = blockIdx.x;
  const int bh = ((id & 7) << 2) + ((id >> 3) & 3);   // XCD-aware
  const int qp = id >> 5;                             // 0..15
  const size_t bhL = (size_t)bh * L_;
  const int b2 = bh >> 4, h2 = bh & 15;
  _Float16* pw = p_s + w * 2176;

  for (int hp = 0; hp < 2; ++hp) {
    const int qt = hp ? (31 - qp) : qp;
    const int l0 = qt * 64;
    const int nq = l0 >> 7;
    const int rowA = l0 + w * 16 + r;

    float m = -1e30f, den = 0.f;
    f4 oacc[4];
    #pragma unroll
    for (int t = 0; t < 4; ++t) oacc[t] = (f4){0.f, 0.f, 0.f, 0.f};

    for (int n = 0; n <= nq; ++n) {
      if (n < nq) {
        // ---------------- off-diagonal rank-1 chunk ----------------
        __syncthreads();
        {
          int d = tid >> 2, c8 = (tid & 3) * 8;
          const _Float16* src = VT + ((size_t)bh * HD_ + d) * L_ + n * C_ + c8;
          #pragma unroll
          for (int jj = 0; jj < 4; ++jj)
            *(int4*)&kv_s[d * 136 + c8 + jj * 32] = *(const int4*)(src + jj * 32);
          if (tid < 128) c2t_s[tid] = C2T[((size_t)bh * N_ + n) * C_ + tid];
        }
        __syncthreads();
        float tval = T2C[(bhL + rowA) * N_ + n] * INV_SCALE;
        float mxv = C2TMX[bh * N_ + n], mnv = C2TMN[bh * N_ + n];
        float cmax = fmaxf(tval * mxv, tval * mnv);
        float mnew = fmaxf(m, cmax);
        float alpha = __expf(m - mnew);
        m = mnew;
        float al0 = __shfl(alpha, (q << 2) + 0);
        float al1 = __shfl(alpha, (q << 2) + 1);
        float al2 = __shfl(alpha, (q << 2) + 2);
        float al3 = __shfl(alpha, (q << 2) + 3);
        #pragma unroll
        for (int t = 0; t < 4; ++t) {
          oacc[t][0] *= al0; oacc[t][1] *= al1;
          oacc[t][2] *= al2; oacc[t][3] *= al3;
        }
        float csum = 0.f;
        #pragma unroll
        for (int s = 0; s < 4; ++s) {
          const float* cp = &c2t_s[s * 32 + q * 8];
          float4 ca = *(const float4*)cp;
          float4 cb = *(const float4*)(cp + 4);
          float p0 = __expf(tval * ca.x - mnew), p1 = __expf(tval * ca.y - mnew);
          float p2 = __expf(tval * ca.z - mnew), p3 = __expf(tval * ca.w - mnew);
          float p4 = __expf(tval * cb.x - mnew), p5 = __expf(tval * cb.y - mnew);
          float p6 = __expf(tval * cb.z - mnew), p7 = __expf(tval * cb.w - mnew);
          csum += p0 + p1 + p2 + p3 + p4 + p5 + p6 + p7;
          h8 pa = { (_Float16)p0, (_Float16)p1, (_Float16)p2, (_Float16)p3,
                    (_Float16)p4, (_Float16)p5, (_Float16)p6, (_Float16)p7 };
          #pragma unroll
          for (int t = 0; t < 4; ++t) {
            h8 vb = *(const h8*)&kv_s[(t * 16 + r) * 136 + s * 32 + q * 8];
            oacc[t] = MFMA16(pa, vb, oacc[t]);
          }
        }
        csum += __shfl_xor(csum, 16);
        csum += __shfl_xor(csum, 32);
        den = den * alpha + csum;
      } else {
        // ---------------- diagonal chunk: direct QK^T ----------------
        __syncthreads();
        {
          int c = tid >> 1, dc = (tid & 1) * 32;
          const _Float16* src = Kh + (bhL + n * C_ + c) * HD_ + dc;
          #pragma unroll
          for (int jj = 0; jj < 4; ++jj)
            *(int4*)&kv_s[c * 72 + dc + jj * 8] = *(const int4*)(src + jj * 8);
        }
        __syncthreads();
        f4 sc[8];
        #pragma unroll
        for (int u = 0; u < 8; ++u) sc[u] = (f4){0.f, 0.f, 0.f, 0.f};
        #pragma unroll
        for (int s2 = 0; s2 < 2; ++s2) {
          h8 qa = *(const h8*)(Qh + (bhL + rowA) * HD_ + s2 * 32 + q * 8);
          #pragma unroll
          for (int u = 0; u < 8; ++u) {
            h8 kb = *(const h8*)&kv_s[(u * 16 + r) * 72 + s2 * 32 + q * 8];
            sc[u] = MFMA16(qa, kb, sc[u]);
          }
        }
        float rm[4] = {-1e30f, -1e30f, -1e30f, -1e30f};
        #pragma unroll
        for (int u = 0; u < 8; ++u) {
          int col = n * C_ + u * 16 + r;
          #pragma unroll
          for (int i = 0; i < 4; ++i) {
            int row = l0 + w * 16 + q * 4 + i;
            float v = sc[u][i] * INV_SCALE;
            v = (col <= row) ? v : -1e30f;
            sc[u][i] = v;
            rm[i] = fmaxf(rm[i], v);
          }
        }
        #pragma unroll
        for (int i = 0; i < 4; ++i) {
          rm[i] = fmaxf(rm[i], __shfl_xor(rm[i], 1));
          rm[i] = fmaxf(rm[i], __shfl_xor(rm[i], 2));
          rm[i] = fmaxf(rm[i], __shfl_xor(rm[i], 4));
          rm[i] = fmaxf(rm[i], __shfl_xor(rm[i], 8));
        }
        int srcl = (r >> 2) << 4;
        int ri = r & 3;
        float t0 = __shfl(rm[0], srcl), t1 = __shfl(rm[1], srcl);
        float t2 = __shfl(rm[2], srcl), t3 = __shfl(rm[3], srcl);
        float myrm = ri == 0 ? t0 : ri == 1 ? t1 : ri == 2 ? t2 : t3;
        float mnew = fmaxf(m, myrm);
        float alpha = __expf(m - mnew);
        m = mnew;
        float mrow[4], al[4];
        #pragma unroll
        for (int i = 0; i < 4; ++i) {
          mrow[i] = __shfl(mnew, (q << 2) + i);
          al[i]   = __shfl(alpha, (q << 2) + i);
        }
        float cs[4] = {0.f, 0.f, 0.f, 0.f};
        #pragma unroll
        for (int u = 0; u < 8; ++u)
          #pragma unroll
          for (int i = 0; i < 4; ++i) {
            float v = sc[u][i];
            float p = (v > -1e29f) ? __expf(v - mrow[i]) : 0.f;
            cs[i] += p;
            pw[(q * 4 + i) * 136 + u * 16 + r] = (_Float16)p;
          }
        #pragma unroll
        for (int i = 0; i < 4; ++i) {
          cs[i] += __shfl_xor(cs[i], 1);
          cs[i] += __shfl_xor(cs[i], 2);
          cs[i] += __shfl_xor(cs[i], 4);
          cs[i] += __shfl_xor(cs[i], 8);
        }
        float c0 = __shfl(cs[0], srcl), c1 = __shfl(cs[1], srcl);
        float c2 = __shfl(cs[2], srcl), c3 = __shfl(cs[3], srcl);
        float mycs = ri == 0 ? c0 : ri == 1 ? c1 : ri == 2 ? c2 : c3;
        den = den * alpha + mycs;
        #pragma unroll
        for (int t = 0; t < 4; ++t) {
          oacc[t][0] *= al[0]; oacc[t][1] *= al[1];
          oacc[t][2] *= al[2]; oacc[t][3] *= al[3];
        }
        // restage V over K tile
        __syncthreads();
        {
          int d = tid >> 2, c8 = (tid & 3) * 8;
          const _Float16* src = VT + ((size_t)bh * HD_ + d) * L_ + n * C_ + c8;
          #pragma unroll
          for (int jj = 0; jj < 4; ++jj)
            *(int4*)&kv_s[d * 136 + c8 + jj * 32] = *(const int4*)(src + jj * 32);
        }
        __syncthreads();
        #pragma unroll
        for (int s = 0; s < 4; ++s) {
          h8 pa = *(const h8*)&pw[r * 136 + s * 32 + q * 8];
          #pragma unroll
          for (int t = 0; t < 4; ++t) {
            h8 vb = *(const h8*)&kv_s[(t * 16 + r) * 136 + s * 32 + q * 8];
            oacc[t] = MFMA16(pa, vb, oacc[t]);
          }
        }
      }
    }

    // -------- masked-zero (score=0) closed-form contribution + output --------
    int cnt = (L_ - 1) - rowA;
    float mfin = (cnt > 0) ? fmaxf(m, 0.f) : m;
    float alphaf = __expf(m - mfin);
    float e0 = (cnt > 0) ? __expf(-mfin) : 0.f;
    den = den * alphaf + e0 * (float)cnt;
    float alf[4], e0r[4], dnr[4];
    #pragma unroll
    for (int i = 0; i < 4; ++i) {
      alf[i] = __shfl(alphaf, (q << 2) + i);
      e0r[i] = __shfl(e0,     (q << 2) + i);
      dnr[i] = __shfl(den,    (q << 2) + i);
    }
    #pragma unroll
    for (int t = 0; t < 4; ++t) {
      int d = t * 16 + r;
      float csf = CSUF[((size_t)bh * N_ + nq) * HD_ + d];
      #pragma unroll
      for (int i = 0; i < 4; ++i) {
        int row = l0 + w * 16 + q * 4 + i;
        float suf = SUF2[(bhL + row) * HD_ + d] + csf;
        float o = (oacc[t][i] * alf[i] + e0r[i] * suf) / dnr[i];
        AOh[((size_t)b2 * L_ + row) * D_ + h2 * HD_ + d] = (_Float16)o;
      }
    }
  }
}

// ---------------------------------------------------------------------------
extern "C" void kernel_launch(void* const* d_in, const int* in_sizes, int n_in,
                              void* d_out, int out_size, void* d_ws, size_t ws_size,
                              hipStream_t stream)
{
  (void)in_sizes; (void)n_in; (void)out_size; (void)ws_size;
  const float* x     = (const float*)d_in[0];
  const float* w_qkv = (const float*)d_in[1];
  const float* b_qkv = (const float*)d_in[2];
  const float* w_o   = (const float*)d_in[3];
  const float* b_o   = (const float*)d_in[4];
  float* out = (float*)d_out;

  char* p = (char*)d_ws;
  _Float16* xh   = (_Float16*)p; p += (size_t)4194304 * 2;
  _Float16* wqT  = (_Float16*)p; p += (size_t)3145728 * 2;
  _Float16* woT  = (_Float16*)p; p += (size_t)1048576 * 2;
  _Float16* Qh   = (_Float16*)p; p += (size_t)4194304 * 2;
  _Float16* Kh   = (_Float16*)p; p += (size_t)4194304 * 2;
  float*    Vf   = (float*)p;    p += (size_t)4194304 * 4;
  _Float16* VT   = (_Float16*)p; p += (size_t)4194304 * 2;
  _Float16* AOh  = (_Float16*)p; p += (size_t)4194304 * 2;
  float*    SUF2 = (float*)p;    p += (size_t)4194304 * 4;
  float*    T2C  = (float*)p;    p += (size_t)1048576 * 4;
  float*    C2T  = (float*)p;    p += (size_t)65536 * 4;
  float*    QP   = (float*)p;    p += (size_t)32768 * 4;
  float*    KP   = (float*)p;    p += (size_t)32768 * 4;
  float*    VCS  = (float*)p;    p += (size_t)32768 * 4;
  float*    CSUF = (float*)p;    p += (size_t)32768 * 4;
  float*    MXa  = (float*)p;    p += (size_t)512 * 4;
  float*    MNa  = (float*)p;    p += (size_t)512 * 4;

  cvtx_kernel<<<4096, 256, 0, stream>>>(x, xh);
  wt_kernel<<<dim3(96, 32), 256, 0, stream>>>(w_qkv, wqT, 3 * D_, D_);
  wt_kernel<<<dim3(32, 32), 256, 0, stream>>>(w_o, woT, D_, D_);
  gemm16_kernel<<<dim3(24, 32), 256, 0, stream>>>(
      xh, wqT, b_qkv, Qh, Kh, Vf, nullptr, D_, 0);
  pool_kernel<<<B_ * H_ * N_, 64, 0, stream>>>(Qh, Kh, QP, KP);
  suf_kernel<<<B_ * H_ * N_, 256, 0, stream>>>(Vf, SUF2, VCS);
  csuf_kernel<<<B_ * H_, 64, 0, stream>>>(VCS, CSUF);
  vt_kernel<<<dim3(L_ / 128, B_ * H_), 256, 0, stream>>>(Vf, VT);
  c2t_kernel<<<B_ * H_ * N_, 128, 0, stream>>>(QP, Kh, C2T, MXa, MNa);
  t2c_kernel<<<dim3(B_ * H_, L_ / 128), 256, 0, stream>>>(Qh, KP, T2C);
  attn2_kernel<<<512, 256, 0, stream>>>(
      Qh, Kh, VT, T2C, C2T, MXa, MNa, CSUF, SUF2, AOh);
  gemm16_kernel<<<dim3(8, 32), 256, 0, stream>>>(
      AOh, woT, b_o, nullptr, nullptr, nullptr, out, D_, 1);
}

// Round 4
// 245.975 us; speedup vs baseline: 4.3610x; 1.0438x over previous
//
#include <hip/hip_runtime.h>
#include <math.h>

#define B_   2
#define L_   2048
#define D_   1024
#define H_   16
#define HD_  64
#define C_   128
#define N_   16
#define INV_SCALE 0.03125f   // 1/sqrt(1024)

typedef _Float16 h8 __attribute__((ext_vector_type(8)));
typedef _Float16 h4 __attribute__((ext_vector_type(4)));
typedef float    f4 __attribute__((ext_vector_type(4)));

#define MFMA16(a, b, c) __builtin_amdgcn_mfma_f32_16x16x32_f16((a), (b), (c), 0, 0, 0)

__device__ __forceinline__ void gl_lds16(const void* g, void* l) {
  __builtin_amdgcn_global_load_lds(
      (const __attribute__((address_space(1))) void*)g,
      (__attribute__((address_space(3))) void*)l, 16, 0, 0);
}

// ---------------------------------------------------------------------------
// x fp32 -> fp16 flat
// ---------------------------------------------------------------------------
__global__ __launch_bounds__(256) void cvtx_kernel(const float* __restrict__ X,
                                                   _Float16* __restrict__ Xh)
{
  int i = (blockIdx.x * 256 + threadIdx.x) * 4;
  float4 v = *(const float4*)(X + i);
  h4 o = { (_Float16)v.x, (_Float16)v.y, (_Float16)v.z, (_Float16)v.w };
  *(h4*)(Xh + i) = o;
}

// ---------------------------------------------------------------------------
// W (Kd x Nc, fp32) -> WT (Nc x Kd, fp16) tiled transpose
// ---------------------------------------------------------------------------
__global__ __launch_bounds__(256) void wt_kernel(const float* __restrict__ W,
                                                 _Float16* __restrict__ WT,
                                                 int Nc, int Kd)
{
  __shared__ float ts[32][36];
  const int tid = threadIdx.x;
  const int n0 = blockIdx.x * 32, k0 = blockIdx.y * 32;
  {
    int kr = tid >> 3, nc4 = (tid & 7) * 4;
    float4 v = *(const float4*)&W[(size_t)(k0 + kr) * Nc + n0 + nc4];
    ts[kr][nc4+0] = v.x; ts[kr][nc4+1] = v.y; ts[kr][nc4+2] = v.z; ts[kr][nc4+3] = v.w;
  }
  __syncthreads();
  {
    int nr = tid >> 3, kc4 = (tid & 7) * 4;
    h4 o = { (_Float16)ts[kc4+0][nr], (_Float16)ts[kc4+1][nr],
             (_Float16)ts[kc4+2][nr], (_Float16)ts[kc4+3][nr] };
    *(h4*)&WT[(size_t)(n0 + nr) * Kd + k0 + kc4] = o;
  }
}

// ---------------------------------------------------------------------------
// fp16 MFMA GEMM, double-buffered global_load_lds staging, 1 barrier/K-step.
// LDS: row-major stride 32 fp16; 16B k-chunks XOR-swizzled by (row>>1)&3 so
// b128 reads hit all 8 bank-quads in every 8-lane group (conflict-free).
// mode 0: scatter -> Qh/Kh fp16 head layout + VT fp16 TRANSPOSED [bh][d][l].
// mode 1: plain fp32 row-major (Ncols=1024).
// ---------------------------------------------------------------------------
__global__ __launch_bounds__(256) void gemm16_kernel(
    const _Float16* __restrict__ A, const _Float16* __restrict__ Bt,
    const float* __restrict__ bias,
    _Float16* __restrict__ Qh, _Float16* __restrict__ Kh, _Float16* __restrict__ VT,
    float* __restrict__ out, int Kd, int mode)
{
  __shared__ __align__(16) _Float16 As[2][4096];
  __shared__ __align__(16) _Float16 Bs[2][4096];
  const int tid = threadIdx.x;
  const int lane = tid & 63, w = tid >> 6;
  const int wm = w >> 1, wn = w & 1;
  const int q = lane >> 4, r = lane & 15;
  const int m0 = blockIdx.y * 128, n0 = blockIdx.x * 128;

  // staging: lane covers LDS unit tid (pass0) / 256+tid (pass1); row = tid>>2,
  // physical slot tid&3 holds source chunk (tid&3) ^ ((row>>1)&3)
  const int Rr = tid >> 2;
  const int cd = (tid & 3) ^ ((Rr >> 1) & 3);
  const _Float16* Ag = A + (size_t)(m0 + Rr) * Kd + cd * 8;
  const _Float16* Bg = Bt + (size_t)(n0 + Rr) * Kd + cd * 8;
  const size_t rowStep = (size_t)64 * Kd;

  f4 acc[4][4];
  #pragma unroll
  for (int s = 0; s < 4; ++s)
    #pragma unroll
    for (int t = 0; t < 4; ++t) acc[s][t] = (f4){0.f, 0.f, 0.f, 0.f};

  const int nIter = Kd >> 5;
  const int koff = (q ^ ((r >> 1) & 3)) << 3;

  // prologue stage of tile 0
  {
    _Float16* Asl = &As[0][w * 512];
    _Float16* Bsl = &Bs[0][w * 512];
    gl_lds16(Ag, Asl);            gl_lds16(Ag + rowStep, Asl + 2048);
    gl_lds16(Bg, Bsl);            gl_lds16(Bg + rowStep, Bsl + 2048);
  }

  for (int it = 0; it < nIter; ++it) {
    __syncthreads();                       // buf it&1 staged & visible
    if (it + 1 < nIter) {                  // prefetch next tile (overlaps MFMA)
      int kt = (it + 1) << 5;
      _Float16* Asl = &As[(it + 1) & 1][w * 512];
      _Float16* Bsl = &Bs[(it + 1) & 1][w * 512];
      gl_lds16(Ag + kt, Asl);              gl_lds16(Ag + kt + rowStep, Asl + 2048);
      gl_lds16(Bg + kt, Bsl);              gl_lds16(Bg + kt + rowStep, Bsl + 2048);
    }
    const _Float16* Ab = As[it & 1];
    const _Float16* Bb = Bs[it & 1];
    h8 af[4], bf4[4];
    #pragma unroll
    for (int s = 0; s < 4; ++s)
      af[s] = *(const h8*)&Ab[(wm * 64 + s * 16 + r) * 32 + koff];
    #pragma unroll
    for (int t = 0; t < 4; ++t)
      bf4[t] = *(const h8*)&Bb[(wn * 64 + t * 16 + r) * 32 + koff];
    #pragma unroll
    for (int s = 0; s < 4; ++s)
      #pragma unroll
      for (int t = 0; t < 4; ++t)
        acc[s][t] = MFMA16(af[s], bf4[t], acc[s][t]);
  }

  if (mode == 0) {
    #pragma unroll
    for (int t = 0; t < 4; ++t) {
      int gn = n0 + wn * 64 + t * 16 + r;
      float bj = bias[gn];
      int which = gn >> 10, rem = gn & 1023;
      int h2 = rem >> 6, d2 = rem & 63;
      if (which < 2) {
        _Float16* dst = which == 0 ? Qh : Kh;
        #pragma unroll
        for (int s = 0; s < 4; ++s)
          #pragma unroll
          for (int i = 0; i < 4; ++i) {
            int gm = m0 + wm * 64 + s * 16 + q * 4 + i;
            int b2 = gm >> 11, l2 = gm & 2047;
            dst[(((size_t)(b2 * H_ + h2)) * L_ + l2) * HD_ + d2] =
                (_Float16)(acc[s][t][i] + bj);
          }
      } else {
        #pragma unroll
        for (int s = 0; s < 4; ++s) {
          int gm0 = m0 + wm * 64 + s * 16 + q * 4;
          int b2 = gm0 >> 11, l2 = gm0 & 2047;
          h4 hv = { (_Float16)(acc[s][t][0] + bj), (_Float16)(acc[s][t][1] + bj),
                    (_Float16)(acc[s][t][2] + bj), (_Float16)(acc[s][t][3] + bj) };
          *(h4*)&VT[((size_t)(b2 * H_ + h2) * HD_ + d2) * L_ + l2] = hv;
        }
      }
    }
  } else {
    #pragma unroll
    for (int t = 0; t < 4; ++t) {
      int gn = n0 + wn * 64 + t * 16 + r;
      float bj = bias[gn];
      #pragma unroll
      for (int s = 0; s < 4; ++s)
        #pragma unroll
        for (int i = 0; i < 4; ++i) {
          int gm = m0 + wm * 64 + s * 16 + q * 4 + i;
          out[(size_t)gm * 1024 + gn] = acc[s][t][i] + bj;
        }
    }
  }
}

// ---------------------------------------------------------------------------
// Chunk mean pools of Q,K + chunk V totals (from VT). grid BH*N, 64 thr.
// ---------------------------------------------------------------------------
__global__ void pool_kernel(const _Float16* __restrict__ Qh,
                            const _Float16* __restrict__ Kh,
                            const _Float16* __restrict__ VT,
                            float* __restrict__ QP, float* __restrict__ KP,
                            float* __restrict__ VCS)
{
  int bh = blockIdx.x >> 4, n = blockIdx.x & 15, d = threadIdx.x;
  size_t base = ((size_t)bh * L_ + n * C_) * HD_ + d;
  float qs = 0.f, ks = 0.f;
  #pragma unroll 8
  for (int c = 0; c < C_; ++c) {
    qs += (float)Qh[base + (size_t)c * HD_];
    ks += (float)Kh[base + (size_t)c * HD_];
  }
  const _Float16* vr = VT + ((size_t)bh * HD_ + d) * L_ + n * C_;
  float vs = 0.f;
  #pragma unroll
  for (int c = 0; c < C_; c += 8) {
    h8 hv = *(const h8*)(vr + c);
    #pragma unroll
    for (int j = 0; j < 8; ++j) vs += (float)hv[j];
  }
  size_t o = ((size_t)bh * N_ + n) * HD_ + d;
  QP[o] = qs * (1.f / 128.f);
  KP[o] = ks * (1.f / 128.f);
  VCS[o] = vs;
}

// Chunk-level suffix sums. 32 blk, 64 thr.
__global__ void csuf_kernel(const float* __restrict__ VCS, float* __restrict__ CSUF)
{
  int bh = blockIdx.x, d = threadIdx.x;
  float run = 0.f;
  for (int n = N_ - 1; n >= 0; --n) {
    size_t o = ((size_t)bh * N_ + n) * HD_ + d;
    CSUF[o] = run;
    run += VCS[o];
  }
}

// ---------------------------------------------------------------------------
// c2t[bh,n,c] = q_pool . K[c] + per-chunk max/min. grid BH*N, 128 thr.
// ---------------------------------------------------------------------------
__global__ __launch_bounds__(128) void c2t_kernel(
    const float* __restrict__ QP, const _Float16* __restrict__ Kh,
    float* __restrict__ C2T, float* __restrict__ C2TMX, float* __restrict__ C2TMN)
{
  __shared__ float qp_s[64];
  __shared__ float k_s[128 * 69];
  __shared__ float redmx[128];
  __shared__ float redmn[128];
  int bh = blockIdx.x >> 4, n = blockIdx.x & 15, tid = threadIdx.x;
  if (tid < 64) qp_s[tid] = QP[((size_t)bh * N_ + n) * HD_ + tid];
  size_t base = ((size_t)bh * L_ + n * C_) * HD_;
  for (int i = 0; i < 64; ++i) {
    int flat = i * 128 + tid;
    k_s[(flat >> 6) * 69 + (flat & 63)] = (float)Kh[base + flat];
  }
  __syncthreads();
  float s = 0.f;
  #pragma unroll 8
  for (int d = 0; d < 64; ++d) s = fmaf(qp_s[d], k_s[tid * 69 + d], s);
  C2T[((size_t)bh * N_ + n) * C_ + tid] = s;
  redmx[tid] = s; redmn[tid] = s;
  __syncthreads();
  for (int st = 64; st > 0; st >>= 1) {
    if (tid < st) {
      redmx[tid] = fmaxf(redmx[tid], redmx[tid + st]);
      redmn[tid] = fminf(redmn[tid], redmn[tid + st]);
    }
    __syncthreads();
  }
  if (tid == 0) {
    C2TMX[bh * N_ + n] = redmx[0];
    C2TMN[bh * N_ + n] = redmn[0];
  }
}

// ---------------------------------------------------------------------------
// t2c[bh,l,n] = Q[l] . k_pool[n]. grid (BH, L/128), 256 thr.
// ---------------------------------------------------------------------------
__global__ __launch_bounds__(256) void t2c_kernel(
    const _Float16* __restrict__ Qh, const float* __restrict__ KP,
    float* __restrict__ T2C)
{
  __shared__ float kp_s[16 * 68];
  __shared__ float q_s[16 * 68];
  int bh = blockIdx.x, lt = blockIdx.y, tid = threadIdx.x;
  for (int i = tid; i < 1024; i += 256)
    kp_s[(i >> 6) * 68 + (i & 63)] = KP[((size_t)bh * N_) * HD_ + i];
  int li = tid >> 4, n = tid & 15;
  for (int sub = 0; sub < 8; ++sub) {
    int lbase = lt * 128 + sub * 16;
    __syncthreads();
    for (int i = tid; i < 1024; i += 256)
      q_s[(i >> 6) * 68 + (i & 63)] = (float)Qh[((size_t)bh * L_ + lbase) * HD_ + i];
    __syncthreads();
    float s = 0.f;
    #pragma unroll 8
    for (int d = 0; d < 64; ++d) s = fmaf(q_s[li * 68 + d], kp_s[n * 68 + d], s);
    T2C[((size_t)bh * L_ + lbase + li) * N_ + n] = s;
  }
}

// ---------------------------------------------------------------------------
// MFMA attention, load-balanced (tiles qp & 31-qp = 17 chunk-iters/block),
// double-buffered gl_lds staging of V/K tiles (1 barrier per off-diag chunk),
// XOR bank swizzles; within-chunk suffix-V via 0/1-mask MFMA (no SUF2 pass).
// ---------------------------------------------------------------------------
__global__ __launch_bounds__(256) void attn2_kernel(
    const _Float16* __restrict__ Qh, const _Float16* __restrict__ Kh,
    const _Float16* __restrict__ VT,
    const float* __restrict__ T2C, const float* __restrict__ C2T,
    const float* __restrict__ C2TMX, const float* __restrict__ C2TMN,
    const float* __restrict__ CSUF, _Float16* __restrict__ AOh)
{
  __shared__ __align__(16) _Float16 kv_s[2][8192];  // V: [d][c]@128  K: [c][d]@64
  __shared__ __align__(16) _Float16 p_s[4 * 16 * 136];
  __shared__ __align__(16) float c2t_s[2][128];

  const int tid = threadIdx.x;
  const int w = tid >> 6, lane = tid & 63;
  const int q = lane >> 4, r = lane & 15;
  const int id = blockIdx.x;
  const int bh = ((id & 7) << 2) + ((id >> 3) & 3);   // XCD-aware decode
  const int qp = id >> 5;                             // 0..15
  const size_t bhL = (size_t)bh * L_;
  const int b2 = bh >> 4, h2 = bh & 15;
  _Float16* pw = p_s + w * 2176;
  const int r7 = r & 7;

  // staging source decode (per lane, per 16B unit f = j*256 + tid)
  auto stageV = [&](int bf, int n) {
    #pragma unroll
    for (int j = 0; j < 4; ++j) {
      int f = j * 256 + tid;
      int d = f >> 4, p = f & 15;
      int c16 = p ^ (d & 7);
      gl_lds16(VT + ((size_t)bh * HD_ + d) * L_ + n * C_ + c16 * 8,
               &kv_s[bf][(size_t)(j * 256 + w * 64) * 8]);
    }
  };
  auto stageK = [&](int bf, int n) {
    #pragma unroll
    for (int j = 0; j < 4; ++j) {
      int f = j * 256 + tid;
      int c = f >> 3, p = f & 7;
      int ck = p ^ (c & 7);
      gl_lds16(Kh + (bhL + n * C_ + c) * HD_ + ck * 8,
               &kv_s[bf][(size_t)(j * 256 + w * 64) * 8]);
    }
  };
  auto stageC = [&](int bf, int n) {
    if (tid < 32)
      gl_lds16(C2T + ((size_t)bh * N_ + n) * C_ + lane * 4, &c2t_s[bf][0]);
  };

  for (int hp = 0; hp < 2; ++hp) {
    const int qt = hp ? (31 - qp) : qp;
    const int l0 = qt * 64;
    const int nq = l0 >> 7;
    const int off = l0 & 127;
    const int rowA = l0 + w * 16 + r;
    const int pcw = off + w * 16 + r;    // mask row position in diag chunk

    float m = -1e30f, den = 0.f;
    f4 oacc[4], sacc[4];
    #pragma unroll
    for (int t = 0; t < 4; ++t) {
      oacc[t] = (f4){0.f, 0.f, 0.f, 0.f};
      sacc[t] = (f4){0.f, 0.f, 0.f, 0.f};
    }
    // prefetch Q row fragments for the diag QK^T
    h8 qa0 = *(const h8*)(Qh + (bhL + rowA) * HD_ + q * 8);
    h8 qa1 = *(const h8*)(Qh + (bhL + rowA) * HD_ + 32 + q * 8);

    __syncthreads();                        // protect buffers from prev tile
    float tvn = 0.f, mxn = 0.f, mnn = 0.f;
    if (nq > 0) {
      stageV(0, 0); stageC(0, 0);
      tvn = T2C[(bhL + rowA) * N_ + 0];
      mxn = C2TMX[bh * N_]; mnn = C2TMN[bh * N_];
    } else {
      stageK(0, 0);
    }

    for (int n = 0; n <= nq; ++n) {
      const int cur = n & 1, nxt = cur ^ 1;
      __syncthreads();                      // buffers for chunk n ready
      if (n + 1 < nq)       { stageV(nxt, n + 1); stageC(nxt, n + 1); }
      else if (n + 1 == nq) { stageK(nxt, nq); }

      if (n < nq) {
        // -------- off-diagonal rank-1 chunk --------
        float tval = tvn * INV_SCALE;
        float mxv = mxn, mnv = mnn;
        if (n + 1 < nq) {
          tvn = T2C[(bhL + rowA) * N_ + n + 1];
          mxn = C2TMX[bh * N_ + n + 1]; mnn = C2TMN[bh * N_ + n + 1];
        }
        float cmax = fmaxf(tval * mxv, tval * mnv);
        float mnew = fmaxf(m, cmax);
        float alpha = __expf(m - mnew);
        m = mnew;
        float al0 = __shfl(alpha, (q << 2) + 0);
        float al1 = __shfl(alpha, (q << 2) + 1);
        float al2 = __shfl(alpha, (q << 2) + 2);
        float al3 = __shfl(alpha, (q << 2) + 3);
        #pragma unroll
        for (int t = 0; t < 4; ++t) {
          oacc[t][0] *= al0; oacc[t][1] *= al1;
          oacc[t][2] *= al2; oacc[t][3] *= al3;
        }
        float csum = 0.f;
        #pragma unroll
        for (int s = 0; s < 4; ++s) {
          const float* cp = &c2t_s[cur][s * 32 + q * 8];
          float4 ca = *(const float4*)cp;
          float4 cb = *(const float4*)(cp + 4);
          float p0 = __expf(tval * ca.x - mnew), p1 = __expf(tval * ca.y - mnew);
          float p2 = __expf(tval * ca.z - mnew), p3 = __expf(tval * ca.w - mnew);
          float p4 = __expf(tval * cb.x - mnew), p5 = __expf(tval * cb.y - mnew);
          float p6 = __expf(tval * cb.z - mnew), p7 = __expf(tval * cb.w - mnew);
          csum += p0 + p1 + p2 + p3 + p4 + p5 + p6 + p7;
          h8 pa = { (_Float16)p0, (_Float16)p1, (_Float16)p2, (_Float16)p3,
                    (_Float16)p4, (_Float16)p5, (_Float16)p6, (_Float16)p7 };
          #pragma unroll
          for (int t = 0; t < 4; ++t) {
            h8 vb = *(const h8*)&kv_s[cur][(t * 16 + r) * 128 +
                                           (((s * 4 + q) ^ r7) << 3)];
            oacc[t] = MFMA16(pa, vb, oacc[t]);
          }
        }
        csum += __shfl_xor(csum, 16);
        csum += __shfl_xor(csum, 32);
        den = den * alpha + csum;
      } else {
        // -------- diagonal chunk: direct QK^T --------
        stageV(nxt, nq);                    // V for PV, lands during QK^T
        f4 sc[8];
        #pragma unroll
        for (int u = 0; u < 8; ++u) sc[u] = (f4){0.f, 0.f, 0.f, 0.f};
        #pragma unroll
        for (int u = 0; u < 8; ++u) {
          h8 kb0 = *(const h8*)&kv_s[cur][(u * 16 + r) * 64 + ((q ^ r7) << 3)];
          h8 kb1 = *(const h8*)&kv_s[cur][(u * 16 + r) * 64 + (((4 + q) ^ r7) << 3)];
          sc[u] = MFMA16(qa0, kb0, sc[u]);
          sc[u] = MFMA16(qa1, kb1, sc[u]);
        }
        float rm[4] = {-1e30f, -1e30f, -1e30f, -1e30f};
        #pragma unroll
        for (int u = 0; u < 8; ++u) {
          int col = n * C_ + u * 16 + r;
          #pragma unroll
          for (int i = 0; i < 4; ++i) {
            int row = l0 + w * 16 + q * 4 + i;
            float v = sc[u][i] * INV_SCALE;
            v = (col <= row) ? v : -1e30f;
            sc[u][i] = v;
            rm[i] = fmaxf(rm[i], v);
          }
        }
        #pragma unroll
        for (int i = 0; i < 4; ++i) {
          rm[i] = fmaxf(rm[i], __shfl_xor(rm[i], 1));
          rm[i] = fmaxf(rm[i], __shfl_xor(rm[i], 2));
          rm[i] = fmaxf(rm[i], __shfl_xor(rm[i], 4));
          rm[i] = fmaxf(rm[i], __shfl_xor(rm[i], 8));
        }
        int srcl = (r >> 2) << 4;
        int ri = r & 3;
        float t0 = __shfl(rm[0], srcl), t1 = __shfl(rm[1], srcl);
        float t2 = __shfl(rm[2], srcl), t3 = __shfl(rm[3], srcl);
        float myrm = ri == 0 ? t0 : ri == 1 ? t1 : ri == 2 ? t2 : t3;
        float mnew = fmaxf(m, myrm);
        float alpha = __expf(m - mnew);
        m = mnew;
        float mrow[4], al[4];
        #pragma unroll
        for (int i = 0; i < 4; ++i) {
          mrow[i] = __shfl(mnew, (q << 2) + i);
          al[i]   = __shfl(alpha, (q << 2) + i);
        }
        float cs[4] = {0.f, 0.f, 0.f, 0.f};
        #pragma unroll
        for (int u = 0; u < 8; ++u)
          #pragma unroll
          for (int i = 0; i < 4; ++i) {
            float v = sc[u][i];
            float p = (v > -1e29f) ? __expf(v - mrow[i]) : 0.f;
            cs[i] += p;
            pw[(q * 4 + i) * 136 + u * 16 + r] = (_Float16)p;
          }
        #pragma unroll
        for (int i = 0; i < 4; ++i) {
          cs[i] += __shfl_xor(cs[i], 1);
          cs[i] += __shfl_xor(cs[i], 2);
          cs[i] += __shfl_xor(cs[i], 4);
          cs[i] += __shfl_xor(cs[i], 8);
        }
        float c0 = __shfl(cs[0], srcl), c1 = __shfl(cs[1], srcl);
        float c2 = __shfl(cs[2], srcl), c3 = __shfl(cs[3], srcl);
        float mycs = ri == 0 ? c0 : ri == 1 ? c1 : ri == 2 ? c2 : c3;
        den = den * alpha + mycs;
        #pragma unroll
        for (int t = 0; t < 4; ++t) {
          oacc[t][0] *= al[0]; oacc[t][1] *= al[1];
          oacc[t][2] *= al[2]; oacc[t][3] *= al[3];
        }
        __syncthreads();                   // V staged + p_s visible
        #pragma unroll
        for (int s = 0; s < 4; ++s) {
          h8 pa = *(const h8*)&pw[r * 136 + s * 32 + q * 8];
          h8 mk;
          #pragma unroll
          for (int j2 = 0; j2 < 8; ++j2)
            mk[j2] = (_Float16)((s * 32 + q * 8 + j2 > pcw) ? 1.f : 0.f);
          #pragma unroll
          for (int t = 0; t < 4; ++t) {
            h8 vb = *(const h8*)&kv_s[nxt][(t * 16 + r) * 128 +
                                           (((s * 4 + q) ^ r7) << 3)];
            oacc[t] = MFMA16(pa, vb, oacc[t]);
            sacc[t] = MFMA16(mk, vb, sacc[t]);   // within-chunk suffix-V
          }
        }
      }
    }

    // -------- masked-zero (score=0) closed-form contribution + output --------
    int cnt = (L_ - 1) - rowA;
    float mfin = (cnt > 0) ? fmaxf(m, 0.f) : m;
    float alphaf = __expf(m - mfin);
    float e0 = (cnt > 0) ? __expf(-mfin) : 0.f;
    den = den * alphaf + e0 * (float)cnt;
    float alf[4], e0r[4], dnr[4];
    #pragma unroll
    for (int i = 0; i < 4; ++i) {
      alf[i] = __shfl(alphaf, (q << 2) + i);
      e0r[i] = __shfl(e0,     (q << 2) + i);
      dnr[i] = __shfl(den,    (q << 2) + i);
    }
    #pragma unroll
    for (int t = 0; t < 4; ++t) {
      int d = t * 16 + r;
      float csf = CSUF[((size_t)bh * N_ + nq) * HD_ + d];
      #pragma unroll
      for (int i = 0; i < 4; ++i) {
        int row = l0 + w * 16 + q * 4 + i;
        float suffix = sacc[t][i] + csf;
        float o = (oacc[t][i] * alf[i] + e0r[i] * suffix) / dnr[i];
        AOh[((size_t)b2 * L_ + row) * D_ + h2 * HD_ + d] = (_Float16)o;
      }
    }
  }
}

// ---------------------------------------------------------------------------
extern "C" void kernel_launch(void* const* d_in, const int* in_sizes, int n_in,
                              void* d_out, int out_size, void* d_ws, size_t ws_size,
                              hipStream_t stream)
{
  (void)in_sizes; (void)n_in; (void)out_size; (void)ws_size;
  const float* x     = (const float*)d_in[0];
  const float* w_qkv = (const float*)d_in[1];
  const float* b_qkv = (const float*)d_in[2];
  const float* w_o   = (const float*)d_in[3];
  const float* b_o   = (const float*)d_in[4];
  float* out = (float*)d_out;

  char* p = (char*)d_ws;
  _Float16* xh   = (_Float16*)p; p += (size_t)4194304 * 2;
  _Float16* wqT  = (_Float16*)p; p += (size_t)3145728 * 2;
  _Float16* woT  = (_Float16*)p; p += (size_t)1048576 * 2;
  _Float16* Qh   = (_Float16*)p; p += (size_t)4194304 * 2;
  _Float16* Kh   = (_Float16*)p; p += (size_t)4194304 * 2;
  _Float16* VT   = (_Float16*)p; p += (size_t)4194304 * 2;
  _Float16* AOh  = (_Float16*)p; p += (size_t)4194304 * 2;
  float*    T2C  = (float*)p;    p += (size_t)1048576 * 4;
  float*    C2T  = (float*)p;    p += (size_t)65536 * 4;
  float*    QP   = (float*)p;    p += (size_t)32768 * 4;
  float*    KP   = (float*)p;    p += (size_t)32768 * 4;
  float*    VCS  = (float*)p;    p += (size_t)32768 * 4;
  float*    CSUF = (float*)p;    p += (size_t)32768 * 4;
  float*    MXa  = (float*)p;    p += (size_t)512 * 4;
  float*    MNa  = (float*)p;    p += (size_t)512 * 4;

  cvtx_kernel<<<4096, 256, 0, stream>>>(x, xh);
  wt_kernel<<<dim3(96, 32), 256, 0, stream>>>(w_qkv, wqT, 3 * D_, D_);
  wt_kernel<<<dim3(32, 32), 256, 0, stream>>>(w_o, woT, D_, D_);
  gemm16_kernel<<<dim3(24, 32), 256, 0, stream>>>(
      xh, wqT, b_qkv, Qh, Kh, VT, nullptr, D_, 0);
  pool_kernel<<<B_ * H_ * N_, 64, 0, stream>>>(Qh, Kh, VT, QP, KP, VCS);
  csuf_kernel<<<B_ * H_, 64, 0, stream>>>(VCS, CSUF);
  c2t_kernel<<<B_ * H_ * N_, 128, 0, stream>>>(QP, Kh, C2T, MXa, MNa);
  t2c_kernel<<<dim3(B_ * H_, L_ / 128), 256, 0, stream>>>(Qh, KP, T2C);
  attn2_kernel<<<512, 256, 0, stream>>>(
      Qh, Kh, VT, T2C, C2T, MXa, MNa, CSUF, AOh);
  gemm16_kernel<<<dim3(8, 32), 256, 0, stream>>>(
      AOh, woT, b_o, nullptr, nullptr, nullptr, out, D_, 1);
}

// Round 5
// 194.319 us; speedup vs baseline: 5.5203x; 1.2658x over previous
//
#include <hip/hip_runtime.h>
#include <math.h>

#define B_   2
#define L_   2048
#define D_   1024
#define H_   16
#define HD_  64
#define C_   128
#define N_   16
#define INV_SCALE 0.03125f   // 1/sqrt(1024)

typedef _Float16 h8 __attribute__((ext_vector_type(8)));
typedef _Float16 h4 __attribute__((ext_vector_type(4)));
typedef float    f4 __attribute__((ext_vector_type(4)));

#define MFMA16(a, b, c) __builtin_amdgcn_mfma_f32_16x16x32_f16((a), (b), (c), 0, 0, 0)

__device__ __forceinline__ void gl_lds16(const void* g, void* l) {
  __builtin_amdgcn_global_load_lds(
      (const __attribute__((address_space(1))) void*)g,
      (__attribute__((address_space(3))) void*)l, 16, 0, 0);
}

// ---------------------------------------------------------------------------
// x fp32 -> fp16 flat
// ---------------------------------------------------------------------------
__global__ __launch_bounds__(256) void cvtx_kernel(const float* __restrict__ X,
                                                   _Float16* __restrict__ Xh)
{
  int i = (blockIdx.x * 256 + threadIdx.x) * 4;
  float4 v = *(const float4*)(X + i);
  h4 o = { (_Float16)v.x, (_Float16)v.y, (_Float16)v.z, (_Float16)v.w };
  *(h4*)(Xh + i) = o;
}

// ---------------------------------------------------------------------------
// W (Kd x Nc, fp32) -> WT (Nc x Kd, fp16) tiled transpose
// ---------------------------------------------------------------------------
__global__ __launch_bounds__(256) void wt_kernel(const float* __restrict__ W,
                                                 _Float16* __restrict__ WT,
                                                 int Nc, int Kd)
{
  __shared__ float ts[32][36];
  const int tid = threadIdx.x;
  const int n0 = blockIdx.x * 32, k0 = blockIdx.y * 32;
  {
    int kr = tid >> 3, nc4 = (tid & 7) * 4;
    float4 v = *(const float4*)&W[(size_t)(k0 + kr) * Nc + n0 + nc4];
    ts[kr][nc4+0] = v.x; ts[kr][nc4+1] = v.y; ts[kr][nc4+2] = v.z; ts[kr][nc4+3] = v.w;
  }
  __syncthreads();
  {
    int nr = tid >> 3, kc4 = (tid & 7) * 4;
    h4 o = { (_Float16)ts[kc4+0][nr], (_Float16)ts[kc4+1][nr],
             (_Float16)ts[kc4+2][nr], (_Float16)ts[kc4+3][nr] };
    *(h4*)&WT[(size_t)(n0 + nr) * Kd + k0 + kc4] = o;
  }
}

// ---------------------------------------------------------------------------
// fp16 MFMA GEMM, double-buffered global_load_lds staging.
// mode 0: scatter -> Qh/Kh head layout + VT transposed, PLUS fused chunk
// pooling: each block covers exactly one (b, chunk) x 128 cols; column sums
// of acc -> QP/KP (mean+bias) and VCS (sum+128*bias).
// mode 1: plain fp32 row-major (Ncols=1024).
// ---------------------------------------------------------------------------
__global__ __launch_bounds__(256) void gemm16_kernel(
    const _Float16* __restrict__ A, const _Float16* __restrict__ Bt,
    const float* __restrict__ bias,
    _Float16* __restrict__ Qh, _Float16* __restrict__ Kh, _Float16* __restrict__ VT,
    float* __restrict__ out,
    float* __restrict__ QP, float* __restrict__ KP, float* __restrict__ VCS,
    int Kd, int mode)
{
  __shared__ __align__(16) _Float16 As[2][4096];
  __shared__ __align__(16) _Float16 Bs[2][4096];
  __shared__ float cred[2][128];
  const int tid = threadIdx.x;
  const int lane = tid & 63, w = tid >> 6;
  const int wm = w >> 1, wn = w & 1;
  const int q = lane >> 4, r = lane & 15;
  const int m0 = blockIdx.y * 128, n0 = blockIdx.x * 128;

  const int Rr = tid >> 2;
  const int cd = (tid & 3) ^ ((Rr >> 1) & 3);
  const _Float16* Ag = A + (size_t)(m0 + Rr) * Kd + cd * 8;
  const _Float16* Bg = Bt + (size_t)(n0 + Rr) * Kd + cd * 8;
  const size_t rowStep = (size_t)64 * Kd;

  f4 acc[4][4];
  #pragma unroll
  for (int s = 0; s < 4; ++s)
    #pragma unroll
    for (int t = 0; t < 4; ++t) acc[s][t] = (f4){0.f, 0.f, 0.f, 0.f};

  const int nIter = Kd >> 5;
  const int koff = (q ^ ((r >> 1) & 3)) << 3;

  {
    _Float16* Asl = &As[0][w * 512];
    _Float16* Bsl = &Bs[0][w * 512];
    gl_lds16(Ag, Asl);            gl_lds16(Ag + rowStep, Asl + 2048);
    gl_lds16(Bg, Bsl);            gl_lds16(Bg + rowStep, Bsl + 2048);
  }

  for (int it = 0; it < nIter; ++it) {
    __syncthreads();
    if (it + 1 < nIter) {
      int kt = (it + 1) << 5;
      _Float16* Asl = &As[(it + 1) & 1][w * 512];
      _Float16* Bsl = &Bs[(it + 1) & 1][w * 512];
      gl_lds16(Ag + kt, Asl);              gl_lds16(Ag + kt + rowStep, Asl + 2048);
      gl_lds16(Bg + kt, Bsl);              gl_lds16(Bg + kt + rowStep, Bsl + 2048);
    }
    const _Float16* Ab = As[it & 1];
    const _Float16* Bb = Bs[it & 1];
    h8 af[4], bf4[4];
    #pragma unroll
    for (int s = 0; s < 4; ++s)
      af[s] = *(const h8*)&Ab[(wm * 64 + s * 16 + r) * 32 + koff];
    #pragma unroll
    for (int t = 0; t < 4; ++t)
      bf4[t] = *(const h8*)&Bb[(wn * 64 + t * 16 + r) * 32 + koff];
    #pragma unroll
    for (int s = 0; s < 4; ++s)
      #pragma unroll
      for (int t = 0; t < 4; ++t)
        acc[s][t] = MFMA16(af[s], bf4[t], acc[s][t]);
  }

  if (mode == 0) {
    #pragma unroll
    for (int t = 0; t < 4; ++t) {
      int gn = n0 + wn * 64 + t * 16 + r;
      float bj = bias[gn];
      int which = gn >> 10, rem = gn & 1023;
      int h2 = rem >> 6, d2 = rem & 63;
      if (which < 2) {
        _Float16* dst = which == 0 ? Qh : Kh;
        #pragma unroll
        for (int s = 0; s < 4; ++s)
          #pragma unroll
          for (int i = 0; i < 4; ++i) {
            int gm = m0 + wm * 64 + s * 16 + q * 4 + i;
            int b2 = gm >> 11, l2 = gm & 2047;
            dst[(((size_t)(b2 * H_ + h2)) * L_ + l2) * HD_ + d2] =
                (_Float16)(acc[s][t][i] + bj);
          }
      } else {
        #pragma unroll
        for (int s = 0; s < 4; ++s) {
          int gm0 = m0 + wm * 64 + s * 16 + q * 4;
          int b2 = gm0 >> 11, l2 = gm0 & 2047;
          h4 hv = { (_Float16)(acc[s][t][0] + bj), (_Float16)(acc[s][t][1] + bj),
                    (_Float16)(acc[s][t][2] + bj), (_Float16)(acc[s][t][3] + bj) };
          *(h4*)&VT[((size_t)(b2 * H_ + h2) * HD_ + d2) * L_ + l2] = hv;
        }
      }
    }
    // -------- fused chunk pooling --------
    float colsum[4];
    #pragma unroll
    for (int t = 0; t < 4; ++t) {
      float s2 = 0.f;
      #pragma unroll
      for (int s = 0; s < 4; ++s)
        #pragma unroll
        for (int i = 0; i < 4; ++i) s2 += acc[s][t][i];
      s2 += __shfl_xor(s2, 16);
      s2 += __shfl_xor(s2, 32);
      colsum[t] = s2;
    }
    if (q == 0) {
      #pragma unroll
      for (int t = 0; t < 4; ++t)
        cred[wm][wn * 64 + t * 16 + r] = colsum[t];
    }
    __syncthreads();
    if (tid < 128) {
      int j = tid;
      float ssum = cred[0][j] + cred[1][j];
      int gn = n0 + j;
      float bj = bias[gn];
      int which = gn >> 10, rem = gn & 1023;
      int h2 = rem >> 6, d2 = rem & 63;
      int b2 = m0 >> 11, nch = (m0 & 2047) >> 7;
      size_t o = (((size_t)(b2 * H_ + h2)) * N_ + nch) * HD_ + d2;
      if (which == 0)      QP[o] = ssum * (1.f / 128.f) + bj;
      else if (which == 1) KP[o] = ssum * (1.f / 128.f) + bj;
      else                 VCS[o] = ssum + 128.f * bj;
    }
  } else {
    #pragma unroll
    for (int t = 0; t < 4; ++t) {
      int gn = n0 + wn * 64 + t * 16 + r;
      float bj = bias[gn];
      #pragma unroll
      for (int s = 0; s < 4; ++s)
        #pragma unroll
        for (int i = 0; i < 4; ++i) {
          int gm = m0 + wm * 64 + s * 16 + q * 4 + i;
          out[(size_t)gm * 1024 + gn] = acc[s][t][i] + bj;
        }
    }
  }
}

// Chunk-level suffix sums. 32 blk, 64 thr.
__global__ void csuf_kernel(const float* __restrict__ VCS, float* __restrict__ CSUF)
{
  int bh = blockIdx.x, d = threadIdx.x;
  float run = 0.f;
  for (int n = N_ - 1; n >= 0; --n) {
    size_t o = ((size_t)bh * N_ + n) * HD_ + d;
    CSUF[o] = run;
    run += VCS[o];
  }
}

// ---------------------------------------------------------------------------
// c2t[bh,n,c] = q_pool . K[c] + per-chunk max/min. grid BH*N, 128 thr,
// direct vectorized register loads (no LDS staging of K).
// ---------------------------------------------------------------------------
__global__ __launch_bounds__(128) void c2t_kernel(
    const float* __restrict__ QP, const _Float16* __restrict__ Kh,
    float* __restrict__ C2T, float* __restrict__ C2TMX, float* __restrict__ C2TMN)
{
  __shared__ float qp_s[64];
  __shared__ float red[4];
  int bh = blockIdx.x >> 4, n = blockIdx.x & 15, tid = threadIdx.x;
  int w = tid >> 6, lane = tid & 63;
  if (tid < 64) qp_s[tid] = QP[((size_t)bh * N_ + n) * HD_ + tid];
  const _Float16* kr = Kh + (((size_t)bh * L_) + n * C_ + tid) * HD_;
  h8 kv[8];
  #pragma unroll
  for (int c8 = 0; c8 < 8; ++c8) kv[c8] = *(const h8*)(kr + c8 * 8);
  __syncthreads();
  float s = 0.f;
  #pragma unroll
  for (int c8 = 0; c8 < 8; ++c8)
    #pragma unroll
    for (int j = 0; j < 8; ++j)
      s = fmaf((float)kv[c8][j], qp_s[c8 * 8 + j], s);
  C2T[((size_t)bh * N_ + n) * C_ + tid] = s;
  float mx = s, mn = s;
  #pragma unroll
  for (int st = 1; st <= 32; st <<= 1) {
    mx = fmaxf(mx, __shfl_xor(mx, st));
    mn = fminf(mn, __shfl_xor(mn, st));
  }
  if (lane == 0) { red[w * 2] = mx; red[w * 2 + 1] = mn; }
  __syncthreads();
  if (tid == 0) {
    C2TMX[bh * N_ + n] = fmaxf(red[0], red[2]);
    C2TMN[bh * N_ + n] = fminf(red[1], red[3]);
  }
}

// ---------------------------------------------------------------------------
// One-pass MFMA attention. Diag chunk FIRST -> final per-row max M is known
// before any accumulation (off-diag chunk maxes are analytic) -> no online
// rescaling chain. T2C folded in via 2 MFMAs (A=k_pool, B=Q-rows). P tile
// overlays the dead K-tile in LDS. Grid 1024 (one 64-row tile per block),
// LPT-ordered (qt=31 first), 4 blocks/CU.
// ---------------------------------------------------------------------------
__global__ __launch_bounds__(256, 4) void attn3_kernel(
    const _Float16* __restrict__ Qh, const _Float16* __restrict__ Kh,
    const _Float16* __restrict__ VT,
    const float* __restrict__ C2T, const float* __restrict__ C2TMX,
    const float* __restrict__ C2TMN, const float* __restrict__ CSUF,
    const float* __restrict__ KP, _Float16* __restrict__ AOh)
{
  __shared__ __align__(16) _Float16 kv_s[2][8192]; // V [d][c]@128 / K [c][d]@64 / P overlay
  __shared__ __align__(16) _Float16 kp_s[1024];    // kp fp16 [n][d]@64, swizzled
  __shared__ __align__(16) float c2t_s[2][128];

  const int tid = threadIdx.x;
  const int w = tid >> 6, lane = tid & 63;
  const int q = lane >> 4, r = lane & 15;
  const int r7 = r & 7;
  const int id = blockIdx.x;
  const int bh = ((id & 7) << 2) + ((id >> 3) & 3);   // XCD-aware
  const int qt = 31 - (id >> 5);                      // LPT: longest first
  const int l0 = qt * 64;
  const int nq = l0 >> 7;
  const int off = l0 & 127;
  const int rowA = l0 + w * 16 + r;
  const int pcw = off + w * 16 + r;
  const size_t bhL = (size_t)bh * L_;
  const int b2 = bh >> 4, h2 = bh & 15;

  auto stageV = [&](int bf, int n) {
    #pragma unroll
    for (int j = 0; j < 4; ++j) {
      int f = j * 256 + tid;
      int d = f >> 4, p = f & 15;
      int c16 = p ^ (d & 7);
      gl_lds16(VT + ((size_t)bh * HD_ + d) * L_ + n * C_ + c16 * 8,
               &kv_s[bf][(size_t)(j * 256 + w * 64) * 8]);
    }
  };
  auto stageK = [&](int bf, int n) {
    #pragma unroll
    for (int j = 0; j < 4; ++j) {
      int f = j * 256 + tid;
      int c = f >> 3, p = f & 7;
      int ck = p ^ (c & 7);
      gl_lds16(Kh + (bhL + n * C_ + c) * HD_ + ck * 8,
               &kv_s[bf][(size_t)(j * 256 + w * 64) * 8]);
    }
  };
  auto stageC = [&](int bf, int n) {
    if (tid < 32)
      gl_lds16(C2T + ((size_t)bh * N_ + n) * C_ + lane * 4, &c2t_s[bf][0]);
  };

  // ---- prologue: kp -> LDS fp16 (swizzled), Q frags, maxes, K stage ----
  {
    int n4 = tid >> 4, d4 = (tid & 15) * 4;
    float4 kpv = *(const float4*)&KP[((size_t)bh * N_ + n4) * HD_ + d4];
    int sd = ((((d4 >> 3) ^ (n4 & 7)) << 3) | (d4 & 7));
    h4 hv = { (_Float16)kpv.x, (_Float16)kpv.y, (_Float16)kpv.z, (_Float16)kpv.w };
    *(h4*)&kp_s[n4 * 64 + sd] = hv;
  }
  h8 qa0 = *(const h8*)(Qh + (bhL + rowA) * HD_ + q * 8);
  h8 qa1 = *(const h8*)(Qh + (bhL + rowA) * HD_ + 32 + q * 8);
  float mxL = C2TMX[bh * N_ + (lane & 15)];
  float mnL = C2TMN[bh * N_ + (lane & 15)];
  stageK(0, nq);
  __syncthreads();

  // ---- tval via MFMA: lane (q,r) reg i = tval[chunk q*4+i] for row rowA ----
  f4 tvacc = (f4){0.f, 0.f, 0.f, 0.f};
  {
    h8 kpa0 = *(const h8*)&kp_s[r * 64 + ((q ^ r7) << 3)];
    h8 kpa1 = *(const h8*)&kp_s[r * 64 + (((4 + q) ^ r7) << 3)];
    tvacc = MFMA16(kpa0, qa0, tvacc);
    tvacc = MFMA16(kpa1, qa1, tvacc);
  }
  float tvs[4];
  #pragma unroll
  for (int i = 0; i < 4; ++i) tvs[i] = tvacc[i] * INV_SCALE;

  // off-diag analytic row max
  float pm = -1e30f;
  #pragma unroll
  for (int i = 0; i < 4; ++i) {
    int n = q * 4 + i;
    float mx = __shfl(mxL, n);
    float mn = __shfl(mnL, n);
    float cm = fmaxf(tvs[i] * mx, tvs[i] * mn);
    pm = (n < nq) ? fmaxf(pm, cm) : pm;
  }
  pm = fmaxf(pm, __shfl_xor(pm, 16));
  pm = fmaxf(pm, __shfl_xor(pm, 32));

  // ---- diag chunk: QK^T ----
  f4 sc[8];
  #pragma unroll
  for (int u = 0; u < 8; ++u) sc[u] = (f4){0.f, 0.f, 0.f, 0.f};
  #pragma unroll
  for (int u = 0; u < 8; ++u) {
    h8 kb0 = *(const h8*)&kv_s[0][(u * 16 + r) * 64 + ((q ^ r7) << 3)];
    h8 kb1 = *(const h8*)&kv_s[0][(u * 16 + r) * 64 + (((4 + q) ^ r7) << 3)];
    sc[u] = MFMA16(qa0, kb0, sc[u]);
    sc[u] = MFMA16(qa1, kb1, sc[u]);
  }
  stageV(1, nq);                         // V for diag PV, lands during math

  float rm[4] = {-1e30f, -1e30f, -1e30f, -1e30f};
  #pragma unroll
  for (int u = 0; u < 8; ++u) {
    int col = nq * C_ + u * 16 + r;
    #pragma unroll
    for (int i = 0; i < 4; ++i) {
      int row = l0 + w * 16 + q * 4 + i;
      float v = sc[u][i] * INV_SCALE;
      v = (col <= row) ? v : -1e30f;
      sc[u][i] = v;
      rm[i] = fmaxf(rm[i], v);
    }
  }
  #pragma unroll
  for (int i = 0; i < 4; ++i) {
    rm[i] = fmaxf(rm[i], __shfl_xor(rm[i], 1));
    rm[i] = fmaxf(rm[i], __shfl_xor(rm[i], 2));
    rm[i] = fmaxf(rm[i], __shfl_xor(rm[i], 4));
    rm[i] = fmaxf(rm[i], __shfl_xor(rm[i], 8));
  }
  const int srcl = (r >> 2) << 4;
  const int ri = r & 3;
  float t0 = __shfl(rm[0], srcl), t1 = __shfl(rm[1], srcl);
  float t2 = __shfl(rm[2], srcl), t3 = __shfl(rm[3], srcl);
  float myrm = ri == 0 ? t0 : ri == 1 ? t1 : ri == 2 ? t2 : t3;

  // ---- FINAL per-row max, known before any accumulation ----
  const float M = fmaxf(fmaxf(pm, myrm), 0.f);
  const float e0 = __expf(-M);
  float Mc[4];
  #pragma unroll
  for (int i = 0; i < 4; ++i) Mc[i] = __shfl(M, (q << 2) + i);

  // diag exp (in place) + row sums
  float cs[4] = {0.f, 0.f, 0.f, 0.f};
  #pragma unroll
  for (int u = 0; u < 8; ++u)
    #pragma unroll
    for (int i = 0; i < 4; ++i) {
      float v = sc[u][i];
      float p = (v > -1e29f) ? __expf(v - Mc[i]) : 0.f;
      sc[u][i] = p;
      cs[i] += p;
    }
  #pragma unroll
  for (int i = 0; i < 4; ++i) {
    cs[i] += __shfl_xor(cs[i], 1);
    cs[i] += __shfl_xor(cs[i], 2);
    cs[i] += __shfl_xor(cs[i], 4);
    cs[i] += __shfl_xor(cs[i], 8);
  }
  float c0 = __shfl(cs[0], srcl), c1 = __shfl(cs[1], srcl);
  float c2 = __shfl(cs[2], srcl), c3 = __shfl(cs[3], srcl);
  float den = ri == 0 ? c0 : ri == 1 ? c1 : ri == 2 ? c2 : c3;

  __syncthreads();   // all K-tile reads done; V staged; P overlay now safe
  // write P (own-wave region overlaying the K-tile), swizzled row-major
  _Float16* pw = &kv_s[0][w * 2048];
  #pragma unroll
  for (int u = 0; u < 8; ++u)
    #pragma unroll
    for (int i = 0; i < 4; ++i) {
      int row = q * 4 + i, col = u * 16 + r;
      pw[row * 128 + ((((col >> 3) ^ (row & 7)) << 3) | (col & 7))] =
          (_Float16)sc[u][i];
    }

  f4 oacc[4], sacc[4];
  #pragma unroll
  for (int t = 0; t < 4; ++t) {
    oacc[t] = (f4){0.f, 0.f, 0.f, 0.f};
    sacc[t] = (f4){0.f, 0.f, 0.f, 0.f};
  }
  #pragma unroll
  for (int s = 0; s < 4; ++s) {
    h8 pa = *(const h8*)&pw[r * 128 + (((s * 4 + q) ^ r7) << 3)];
    h8 mk;
    #pragma unroll
    for (int j2 = 0; j2 < 8; ++j2)
      mk[j2] = (_Float16)((s * 32 + q * 8 + j2 > pcw) ? 1.f : 0.f);
    #pragma unroll
    for (int t = 0; t < 4; ++t) {
      h8 vb = *(const h8*)&kv_s[1][(t * 16 + r) * 128 + (((s * 4 + q) ^ r7) << 3)];
      oacc[t] = MFMA16(pa, vb, oacc[t]);
      sacc[t] = MFMA16(mk, vb, sacc[t]);    // within-chunk suffix-V
    }
  }

  __syncthreads();   // P/V reads done; kv_s[0] reusable
  if (nq >= 1) { stageV(0, nq - 1); stageC(0, nq - 1); }

  // ---- off-diagonal chunks, fixed M, no rescaling ----
  for (int n = nq - 1; n >= 0; --n) {
    const int cur = (nq - 1 - n) & 1, nxt = cur ^ 1;
    __syncthreads();
    if (n >= 1) { stageV(nxt, n - 1); stageC(nxt, n - 1); }
    int i0 = n & 3;
    float tvx = i0 == 0 ? tvs[0] : i0 == 1 ? tvs[1] : i0 == 2 ? tvs[2] : tvs[3];
    float tvn = __shfl(tvx, ((n >> 2) << 4) + r);
    float csum = 0.f;
    #pragma unroll
    for (int s = 0; s < 4; ++s) {
      const float* cp = &c2t_s[cur][s * 32 + q * 8];
      float4 ca = *(const float4*)cp;
      float4 cb = *(const float4*)(cp + 4);
      float p0 = __expf(tvn * ca.x - M), p1 = __expf(tvn * ca.y - M);
      float p2 = __expf(tvn * ca.z - M), p3 = __expf(tvn * ca.w - M);
      float p4 = __expf(tvn * cb.x - M), p5 = __expf(tvn * cb.y - M);
      float p6 = __expf(tvn * cb.z - M), p7 = __expf(tvn * cb.w - M);
      csum += p0 + p1 + p2 + p3 + p4 + p5 + p6 + p7;
      h8 pa = { (_Float16)p0, (_Float16)p1, (_Float16)p2, (_Float16)p3,
                (_Float16)p4, (_Float16)p5, (_Float16)p6, (_Float16)p7 };
      #pragma unroll
      for (int t = 0; t < 4; ++t) {
        h8 vb = *(const h8*)&kv_s[cur][(t * 16 + r) * 128 + (((s * 4 + q) ^ r7) << 3)];
        oacc[t] = MFMA16(pa, vb, oacc[t]);
      }
    }
    csum += __shfl_xor(csum, 16);
    csum += __shfl_xor(csum, 32);
    den += csum;
  }

  // ---- masked-zero closed form + output ----
  int cnt = (L_ - 1) - rowA;
  den += e0 * (float)cnt;
  float e0r[4], dnr[4];
  #pragma unroll
  for (int i = 0; i < 4; ++i) {
    e0r[i] = __shfl(e0,  (q << 2) + i);
    dnr[i] = __shfl(den, (q << 2) + i);
  }
  #pragma unroll
  for (int t = 0; t < 4; ++t) {
    int d = t * 16 + r;
    float csf = CSUF[((size_t)bh * N_ + nq) * HD_ + d];
    #pragma unroll
    for (int i = 0; i < 4; ++i) {
      int row = l0 + w * 16 + q * 4 + i;
      float suffix = sacc[t][i] + csf;
      float o = (oacc[t][i] + e0r[i] * suffix) / dnr[i];
      AOh[((size_t)b2 * L_ + row) * D_ + h2 * HD_ + d] = (_Float16)o;
    }
  }
}

// ---------------------------------------------------------------------------
extern "C" void kernel_launch(void* const* d_in, const int* in_sizes, int n_in,
                              void* d_out, int out_size, void* d_ws, size_t ws_size,
                              hipStream_t stream)
{
  (void)in_sizes; (void)n_in; (void)out_size; (void)ws_size;
  const float* x     = (const float*)d_in[0];
  const float* w_qkv = (const float*)d_in[1];
  const float* b_qkv = (const float*)d_in[2];
  const float* w_o   = (const float*)d_in[3];
  const float* b_o   = (const float*)d_in[4];
  float* out = (float*)d_out;

  char* p = (char*)d_ws;
  _Float16* xh   = (_Float16*)p; p += (size_t)4194304 * 2;
  _Float16* wqT  = (_Float16*)p; p += (size_t)3145728 * 2;
  _Float16* woT  = (_Float16*)p; p += (size_t)1048576 * 2;
  _Float16* Qh   = (_Float16*)p; p += (size_t)4194304 * 2;
  _Float16* Kh   = (_Float16*)p; p += (size_t)4194304 * 2;
  _Float16* VT   = (_Float16*)p; p += (size_t)4194304 * 2;
  _Float16* AOh  = (_Float16*)p; p += (size_t)4194304 * 2;
  float*    C2T  = (float*)p;    p += (size_t)65536 * 4;
  float*    QP   = (float*)p;    p += (size_t)32768 * 4;
  float*    KP   = (float*)p;    p += (size_t)32768 * 4;
  float*    VCS  = (float*)p;    p += (size_t)32768 * 4;
  float*    CSUF = (float*)p;    p += (size_t)32768 * 4;
  float*    MXa  = (float*)p;    p += (size_t)512 * 4;
  float*    MNa  = (float*)p;    p += (size_t)512 * 4;

  cvtx_kernel<<<4096, 256, 0, stream>>>(x, xh);
  wt_kernel<<<dim3(96, 32), 256, 0, stream>>>(w_qkv, wqT, 3 * D_, D_);
  wt_kernel<<<dim3(32, 32), 256, 0, stream>>>(w_o, woT, D_, D_);
  gemm16_kernel<<<dim3(24, 32), 256, 0, stream>>>(
      xh, wqT, b_qkv, Qh, Kh, VT, nullptr, QP, KP, VCS, D_, 0);
  csuf_kernel<<<B_ * H_, 64, 0, stream>>>(VCS, CSUF);
  c2t_kernel<<<B_ * H_ * N_, 128, 0, stream>>>(QP, Kh, C2T, MXa, MNa);
  attn3_kernel<<<1024, 256, 0, stream>>>(
      Qh, Kh, VT, C2T, MXa, MNa, CSUF, KP, AOh);
  gemm16_kernel<<<dim3(8, 32), 256, 0, stream>>>(
      AOh, woT, b_o, nullptr, nullptr, nullptr, out, nullptr, nullptr, nullptr, D_, 1);
}

// Round 6
// 180.850 us; speedup vs baseline: 5.9314x; 1.0745x over previous
//
#include <hip/hip_runtime.h>
#include <math.h>

#define B_   2
#define L_   2048
#define D_   1024
#define H_   16
#define HD_  64
#define C_   128
#define N_   16
#define INV_SCALE 0.03125f   // 1/sqrt(1024)

typedef _Float16 h8 __attribute__((ext_vector_type(8)));
typedef _Float16 h4 __attribute__((ext_vector_type(4)));
typedef float    f4 __attribute__((ext_vector_type(4)));

#define MFMA16(a, b, c) __builtin_amdgcn_mfma_f32_16x16x32_f16((a), (b), (c), 0, 0, 0)

__device__ __forceinline__ void gl_lds16(const void* g, void* l) {
  __builtin_amdgcn_global_load_lds(
      (const __attribute__((address_space(1))) void*)g,
      (__attribute__((address_space(3))) void*)l, 16, 0, 0);
}

// ---------------------------------------------------------------------------
// x fp32 -> fp16 flat
// ---------------------------------------------------------------------------
__global__ __launch_bounds__(256) void cvtx_kernel(const float* __restrict__ X,
                                                   _Float16* __restrict__ Xh)
{
  int i = (blockIdx.x * 256 + threadIdx.x) * 4;
  float4 v = *(const float4*)(X + i);
  h4 o = { (_Float16)v.x, (_Float16)v.y, (_Float16)v.z, (_Float16)v.w };
  *(h4*)(Xh + i) = o;
}

// ---------------------------------------------------------------------------
// W (Kd x Nc, fp32) -> WT (Nc x Kd, fp16) tiled transpose
// ---------------------------------------------------------------------------
__global__ __launch_bounds__(256) void wt_kernel(const float* __restrict__ W,
                                                 _Float16* __restrict__ WT,
                                                 int Nc, int Kd)
{
  __shared__ float ts[32][36];
  const int tid = threadIdx.x;
  const int n0 = blockIdx.x * 32, k0 = blockIdx.y * 32;
  {
    int kr = tid >> 3, nc4 = (tid & 7) * 4;
    float4 v = *(const float4*)&W[(size_t)(k0 + kr) * Nc + n0 + nc4];
    ts[kr][nc4+0] = v.x; ts[kr][nc4+1] = v.y; ts[kr][nc4+2] = v.z; ts[kr][nc4+3] = v.w;
  }
  __syncthreads();
  {
    int nr = tid >> 3, kc4 = (tid & 7) * 4;
    h4 o = { (_Float16)ts[kc4+0][nr], (_Float16)ts[kc4+1][nr],
             (_Float16)ts[kc4+2][nr], (_Float16)ts[kc4+3][nr] };
    *(h4*)&WT[(size_t)(n0 + nr) * Kd + k0 + kc4] = o;
  }
}

// ---------------------------------------------------------------------------
// fp16 MFMA GEMM, double-buffered global_load_lds staging, XCD-local tiling.
// MT=128 (QKV, mode 0): linear grid 768; XCD j owns n-tiles {3j..3j+2}
//   (B ws 768 KB/XCD). Scatter epilogue -> Qh/Kh + VT + fused chunk pooling.
// MT=64 (out-proj, mode 1): linear grid 512; XCD j owns n-tile j
//   (B ws 256 KB/XCD); 2 blocks/CU.
// ---------------------------------------------------------------------------
template<int MT>
__global__ __launch_bounds__(256, 4) void gemm16_kernel(
    const _Float16* __restrict__ A, const _Float16* __restrict__ Bt,
    const float* __restrict__ bias,
    _Float16* __restrict__ Qh, _Float16* __restrict__ Kh, _Float16* __restrict__ VT,
    float* __restrict__ out,
    float* __restrict__ QP, float* __restrict__ KP, float* __restrict__ VCS,
    int Kd, int mode)
{
  constexpr int SM = MT / 32;              // m-subtiles per wave
  __shared__ __align__(16) _Float16 As[2][MT * 32];
  __shared__ __align__(16) _Float16 Bs[2][4096];
  __shared__ float cred[2][128];
  const int tid = threadIdx.x;
  const int lane = tid & 63, w = tid >> 6;
  const int q = lane >> 4, r = lane & 15;
  const int mb = (w >> 1) * (MT / 2);
  const int nb = (w & 1) * 64;

  int m0, n0;
  {
    const int id = blockIdx.x;
    const int xcd = id & 7, slot = id >> 3;
    if constexpr (MT == 128) {             // 768 blocks: slot 0..95
      n0 = (xcd * 3 + (slot % 3)) * 128;
      m0 = (slot / 3) * 128;
    } else {                               // 512 blocks: slot 0..63
      n0 = xcd * 128;
      m0 = slot * 64;
    }
  }

  const int Rr = tid >> 2;
  const int cd = (tid & 3) ^ ((Rr >> 1) & 3);
  const _Float16* Ag = A + (size_t)(m0 + Rr) * Kd + cd * 8;
  const _Float16* Bg = Bt + (size_t)(n0 + Rr) * Kd + cd * 8;
  const size_t rowStep = (size_t)64 * Kd;

  f4 acc[SM][4];
  #pragma unroll
  for (int s = 0; s < SM; ++s)
    #pragma unroll
    for (int t = 0; t < 4; ++t) acc[s][t] = (f4){0.f, 0.f, 0.f, 0.f};

  const int nIter = Kd >> 5;
  const int koff = (q ^ ((r >> 1) & 3)) << 3;

  auto stage = [&](int bf, int kt) {
    _Float16* Asl = &As[bf][w * 512];
    _Float16* Bsl = &Bs[bf][w * 512];
    gl_lds16(Ag + kt, Asl);
    if constexpr (MT == 128) gl_lds16(Ag + kt + rowStep, Asl + 2048);
    gl_lds16(Bg + kt, Bsl);
    gl_lds16(Bg + kt + rowStep, Bsl + 2048);
  };

  stage(0, 0);

  for (int it = 0; it < nIter; ++it) {
    __syncthreads();
    if (it + 1 < nIter) stage((it + 1) & 1, (it + 1) << 5);
    const _Float16* Ab = As[it & 1];
    const _Float16* Bb = Bs[it & 1];
    h8 af[SM], bf4[4];
    #pragma unroll
    for (int s = 0; s < SM; ++s)
      af[s] = *(const h8*)&Ab[(mb + s * 16 + r) * 32 + koff];
    #pragma unroll
    for (int t = 0; t < 4; ++t)
      bf4[t] = *(const h8*)&Bb[(nb + t * 16 + r) * 32 + koff];
    #pragma unroll
    for (int s = 0; s < SM; ++s)
      #pragma unroll
      for (int t = 0; t < 4; ++t)
        acc[s][t] = MFMA16(af[s], bf4[t], acc[s][t]);
  }

  if (mode == 0) {
    #pragma unroll
    for (int t = 0; t < 4; ++t) {
      int gn = n0 + nb + t * 16 + r;
      float bj = bias[gn];
      int which = gn >> 10, rem = gn & 1023;
      int h2 = rem >> 6, d2 = rem & 63;
      if (which < 2) {
        _Float16* dst = which == 0 ? Qh : Kh;
        #pragma unroll
        for (int s = 0; s < SM; ++s)
          #pragma unroll
          for (int i = 0; i < 4; ++i) {
            int gm = m0 + mb + s * 16 + q * 4 + i;
            int b2 = gm >> 11, l2 = gm & 2047;
            dst[(((size_t)(b2 * H_ + h2)) * L_ + l2) * HD_ + d2] =
                (_Float16)(acc[s][t][i] + bj);
          }
      } else {
        #pragma unroll
        for (int s = 0; s < SM; ++s) {
          int gm0 = m0 + mb + s * 16 + q * 4;
          int b2 = gm0 >> 11, l2 = gm0 & 2047;
          h4 hv = { (_Float16)(acc[s][t][0] + bj), (_Float16)(acc[s][t][1] + bj),
                    (_Float16)(acc[s][t][2] + bj), (_Float16)(acc[s][t][3] + bj) };
          *(h4*)&VT[((size_t)(b2 * H_ + h2) * HD_ + d2) * L_ + l2] = hv;
        }
      }
    }
    // -------- fused chunk pooling --------
    float colsum[4];
    #pragma unroll
    for (int t = 0; t < 4; ++t) {
      float s2 = 0.f;
      #pragma unroll
      for (int s = 0; s < SM; ++s)
        #pragma unroll
        for (int i = 0; i < 4; ++i) s2 += acc[s][t][i];
      s2 += __shfl_xor(s2, 16);
      s2 += __shfl_xor(s2, 32);
      colsum[t] = s2;
    }
    if (q == 0) {
      #pragma unroll
      for (int t = 0; t < 4; ++t)
        cred[w >> 1][nb + t * 16 + r] = colsum[t];
    }
    __syncthreads();
    if (tid < 128) {
      int j = tid;
      float ssum = cred[0][j] + cred[1][j];
      int gn = n0 + j;
      float bj = bias[gn];
      int which = gn >> 10, rem = gn & 1023;
      int h2 = rem >> 6, d2 = rem & 63;
      int b2 = m0 >> 11, nch = (m0 & 2047) >> 7;
      size_t o = (((size_t)(b2 * H_ + h2)) * N_ + nch) * HD_ + d2;
      if (which == 0)      QP[o] = ssum * (1.f / 128.f) + bj;
      else if (which == 1) KP[o] = ssum * (1.f / 128.f) + bj;
      else                 VCS[o] = ssum + 128.f * bj;
    }
  } else {
    #pragma unroll
    for (int t = 0; t < 4; ++t) {
      int gn = n0 + nb + t * 16 + r;
      float bj = bias[gn];
      #pragma unroll
      for (int s = 0; s < SM; ++s)
        #pragma unroll
        for (int i = 0; i < 4; ++i) {
          int gm = m0 + mb + s * 16 + q * 4 + i;
          out[(size_t)gm * 1024 + gn] = acc[s][t][i] + bj;
        }
    }
  }
}

// Chunk-level suffix sums. 32 blk, 64 thr.
__global__ void csuf_kernel(const float* __restrict__ VCS, float* __restrict__ CSUF)
{
  int bh = blockIdx.x, d = threadIdx.x;
  float run = 0.f;
  for (int n = N_ - 1; n >= 0; --n) {
    size_t o = ((size_t)bh * N_ + n) * HD_ + d;
    CSUF[o] = run;
    run += VCS[o];
  }
}

// ---------------------------------------------------------------------------
// c2t[bh,n,c] = q_pool . K[c] + per-chunk max/min. grid BH*N, 128 thr.
// ---------------------------------------------------------------------------
__global__ __launch_bounds__(128) void c2t_kernel(
    const float* __restrict__ QP, const _Float16* __restrict__ Kh,
    float* __restrict__ C2T, float* __restrict__ C2TMX, float* __restrict__ C2TMN)
{
  __shared__ float qp_s[64];
  __shared__ float red[4];
  int bh = blockIdx.x >> 4, n = blockIdx.x & 15, tid = threadIdx.x;
  int w = tid >> 6, lane = tid & 63;
  if (tid < 64) qp_s[tid] = QP[((size_t)bh * N_ + n) * HD_ + tid];
  const _Float16* kr = Kh + (((size_t)bh * L_) + n * C_ + tid) * HD_;
  h8 kv[8];
  #pragma unroll
  for (int c8 = 0; c8 < 8; ++c8) kv[c8] = *(const h8*)(kr + c8 * 8);
  __syncthreads();
  float s = 0.f;
  #pragma unroll
  for (int c8 = 0; c8 < 8; ++c8)
    #pragma unroll
    for (int j = 0; j < 8; ++j)
      s = fmaf((float)kv[c8][j], qp_s[c8 * 8 + j], s);
  C2T[((size_t)bh * N_ + n) * C_ + tid] = s;
  float mx = s, mn = s;
  #pragma unroll
  for (int st = 1; st <= 32; st <<= 1) {
    mx = fmaxf(mx, __shfl_xor(mx, st));
    mn = fminf(mn, __shfl_xor(mn, st));
  }
  if (lane == 0) { red[w * 2] = mx; red[w * 2 + 1] = mn; }
  __syncthreads();
  if (tid == 0) {
    C2TMX[bh * N_ + n] = fmaxf(red[0], red[2]);
    C2TMN[bh * N_ + n] = fminf(red[1], red[3]);
  }
}

// ---------------------------------------------------------------------------
// One-pass MFMA attention (diag-first, final M known up front, no rescale).
// ---------------------------------------------------------------------------
__global__ __launch_bounds__(256, 4) void attn3_kernel(
    const _Float16* __restrict__ Qh, const _Float16* __restrict__ Kh,
    const _Float16* __restrict__ VT,
    const float* __restrict__ C2T, const float* __restrict__ C2TMX,
    const float* __restrict__ C2TMN, const float* __restrict__ CSUF,
    const float* __restrict__ KP, _Float16* __restrict__ AOh)
{
  __shared__ __align__(16) _Float16 kv_s[2][8192]; // V [d][c]@128 / K [c][d]@64 / P overlay
  __shared__ __align__(16) _Float16 kp_s[1024];    // kp fp16 [n][d]@64, swizzled
  __shared__ __align__(16) float c2t_s[2][128];

  const int tid = threadIdx.x;
  const int w = tid >> 6, lane = tid & 63;
  const int q = lane >> 4, r = lane & 15;
  const int r7 = r & 7;
  const int id = blockIdx.x;
  const int bh = ((id & 7) << 2) + ((id >> 3) & 3);   // XCD-aware
  const int qt = 31 - (id >> 5);                      // LPT: longest first
  const int l0 = qt * 64;
  const int nq = l0 >> 7;
  const int off = l0 & 127;
  const int rowA = l0 + w * 16 + r;
  const int pcw = off + w * 16 + r;
  const size_t bhL = (size_t)bh * L_;
  const int b2 = bh >> 4, h2 = bh & 15;

  auto stageV = [&](int bf, int n) {
    #pragma unroll
    for (int j = 0; j < 4; ++j) {
      int f = j * 256 + tid;
      int d = f >> 4, p = f & 15;
      int c16 = p ^ (d & 7);
      gl_lds16(VT + ((size_t)bh * HD_ + d) * L_ + n * C_ + c16 * 8,
               &kv_s[bf][(size_t)(j * 256 + w * 64) * 8]);
    }
  };
  auto stageK = [&](int bf, int n) {
    #pragma unroll
    for (int j = 0; j < 4; ++j) {
      int f = j * 256 + tid;
      int c = f >> 3, p = f & 7;
      int ck = p ^ (c & 7);
      gl_lds16(Kh + (bhL + n * C_ + c) * HD_ + ck * 8,
               &kv_s[bf][(size_t)(j * 256 + w * 64) * 8]);
    }
  };
  auto stageC = [&](int bf, int n) {
    if (tid < 32)
      gl_lds16(C2T + ((size_t)bh * N_ + n) * C_ + lane * 4, &c2t_s[bf][0]);
  };

  // ---- prologue: kp -> LDS fp16 (swizzled), Q frags, maxes, K stage ----
  {
    int n4 = tid >> 4, d4 = (tid & 15) * 4;
    float4 kpv = *(const float4*)&KP[((size_t)bh * N_ + n4) * HD_ + d4];
    int sd = ((((d4 >> 3) ^ (n4 & 7)) << 3) | (d4 & 7));
    h4 hv = { (_Float16)kpv.x, (_Float16)kpv.y, (_Float16)kpv.z, (_Float16)kpv.w };
    *(h4*)&kp_s[n4 * 64 + sd] = hv;
  }
  h8 qa0 = *(const h8*)(Qh + (bhL + rowA) * HD_ + q * 8);
  h8 qa1 = *(const h8*)(Qh + (bhL + rowA) * HD_ + 32 + q * 8);
  float mxL = C2TMX[bh * N_ + (lane & 15)];
  float mnL = C2TMN[bh * N_ + (lane & 15)];
  stageK(0, nq);
  __syncthreads();

  // ---- tval via MFMA: lane (q,r) reg i = tval[chunk q*4+i] for row rowA ----
  f4 tvacc = (f4){0.f, 0.f, 0.f, 0.f};
  {
    h8 kpa0 = *(const h8*)&kp_s[r * 64 + ((q ^ r7) << 3)];
    h8 kpa1 = *(const h8*)&kp_s[r * 64 + (((4 + q) ^ r7) << 3)];
    tvacc = MFMA16(kpa0, qa0, tvacc);
    tvacc = MFMA16(kpa1, qa1, tvacc);
  }
  float tvs[4];
  #pragma unroll
  for (int i = 0; i < 4; ++i) tvs[i] = tvacc[i] * INV_SCALE;

  // off-diag analytic row max
  float pm = -1e30f;
  #pragma unroll
  for (int i = 0; i < 4; ++i) {
    int n = q * 4 + i;
    float mx = __shfl(mxL, n);
    float mn = __shfl(mnL, n);
    float cm = fmaxf(tvs[i] * mx, tvs[i] * mn);
    pm = (n < nq) ? fmaxf(pm, cm) : pm;
  }
  pm = fmaxf(pm, __shfl_xor(pm, 16));
  pm = fmaxf(pm, __shfl_xor(pm, 32));

  // ---- diag chunk: QK^T ----
  f4 sc[8];
  #pragma unroll
  for (int u = 0; u < 8; ++u) sc[u] = (f4){0.f, 0.f, 0.f, 0.f};
  #pragma unroll
  for (int u = 0; u < 8; ++u) {
    h8 kb0 = *(const h8*)&kv_s[0][(u * 16 + r) * 64 + ((q ^ r7) << 3)];
    h8 kb1 = *(const h8*)&kv_s[0][(u * 16 + r) * 64 + (((4 + q) ^ r7) << 3)];
    sc[u] = MFMA16(qa0, kb0, sc[u]);
    sc[u] = MFMA16(qa1, kb1, sc[u]);
  }
  stageV(1, nq);                         // V for diag PV, lands during math

  float rm[4] = {-1e30f, -1e30f, -1e30f, -1e30f};
  #pragma unroll
  for (int u = 0; u < 8; ++u) {
    int col = nq * C_ + u * 16 + r;
    #pragma unroll
    for (int i = 0; i < 4; ++i) {
      int row = l0 + w * 16 + q * 4 + i;
      float v = sc[u][i] * INV_SCALE;
      v = (col <= row) ? v : -1e30f;
      sc[u][i] = v;
      rm[i] = fmaxf(rm[i], v);
    }
  }
  #pragma unroll
  for (int i = 0; i < 4; ++i) {
    rm[i] = fmaxf(rm[i], __shfl_xor(rm[i], 1));
    rm[i] = fmaxf(rm[i], __shfl_xor(rm[i], 2));
    rm[i] = fmaxf(rm[i], __shfl_xor(rm[i], 4));
    rm[i] = fmaxf(rm[i], __shfl_xor(rm[i], 8));
  }
  const int srcl = (r >> 2) << 4;
  const int ri = r & 3;
  float t0 = __shfl(rm[0], srcl), t1 = __shfl(rm[1], srcl);
  float t2 = __shfl(rm[2], srcl), t3 = __shfl(rm[3], srcl);
  float myrm = ri == 0 ? t0 : ri == 1 ? t1 : ri == 2 ? t2 : t3;

  // ---- FINAL per-row max, known before any accumulation ----
  const float M = fmaxf(fmaxf(pm, myrm), 0.f);
  const float e0 = __expf(-M);
  float Mc[4];
  #pragma unroll
  for (int i = 0; i < 4; ++i) Mc[i] = __shfl(M, (q << 2) + i);

  // diag exp (in place) + row sums
  float cs[4] = {0.f, 0.f, 0.f, 0.f};
  #pragma unroll
  for (int u = 0; u < 8; ++u)
    #pragma unroll
    for (int i = 0; i < 4; ++i) {
      float v = sc[u][i];
      float p = (v > -1e29f) ? __expf(v - Mc[i]) : 0.f;
      sc[u][i] = p;
      cs[i] += p;
    }
  #pragma unroll
  for (int i = 0; i < 4; ++i) {
    cs[i] += __shfl_xor(cs[i], 1);
    cs[i] += __shfl_xor(cs[i], 2);
    cs[i] += __shfl_xor(cs[i], 4);
    cs[i] += __shfl_xor(cs[i], 8);
  }
  float c0 = __shfl(cs[0], srcl), c1 = __shfl(cs[1], srcl);
  float c2 = __shfl(cs[2], srcl), c3 = __shfl(cs[3], srcl);
  float den = ri == 0 ? c0 : ri == 1 ? c1 : ri == 2 ? c2 : c3;

  __syncthreads();   // all K-tile reads done; V staged; P overlay now safe
  // write P (own-wave region overlaying the K-tile), swizzled row-major
  _Float16* pw = &kv_s[0][w * 2048];
  #pragma unroll
  for (int u = 0; u < 8; ++u)
    #pragma unroll
    for (int i = 0; i < 4; ++i) {
      int row = q * 4 + i, col = u * 16 + r;
      pw[row * 128 + ((((col >> 3) ^ (row & 7)) << 3) | (col & 7))] =
          (_Float16)sc[u][i];
    }

  f4 oacc[4], sacc[4];
  #pragma unroll
  for (int t = 0; t < 4; ++t) {
    oacc[t] = (f4){0.f, 0.f, 0.f, 0.f};
    sacc[t] = (f4){0.f, 0.f, 0.f, 0.f};
  }
  #pragma unroll
  for (int s = 0; s < 4; ++s) {
    h8 pa = *(const h8*)&pw[r * 128 + (((s * 4 + q) ^ r7) << 3)];
    h8 mk;
    #pragma unroll
    for (int j2 = 0; j2 < 8; ++j2)
      mk[j2] = (_Float16)((s * 32 + q * 8 + j2 > pcw) ? 1.f : 0.f);
    #pragma unroll
    for (int t = 0; t < 4; ++t) {
      h8 vb = *(const h8*)&kv_s[1][(t * 16 + r) * 128 + (((s * 4 + q) ^ r7) << 3)];
      oacc[t] = MFMA16(pa, vb, oacc[t]);
      sacc[t] = MFMA16(mk, vb, sacc[t]);    // within-chunk suffix-V
    }
  }

  __syncthreads();   // P/V reads done; kv_s[0] reusable
  if (nq >= 1) { stageV(0, nq - 1); stageC(0, nq - 1); }

  // ---- off-diagonal chunks, fixed M, no rescaling ----
  for (int n = nq - 1; n >= 0; --n) {
    const int cur = (nq - 1 - n) & 1, nxt = cur ^ 1;
    __syncthreads();
    if (n >= 1) { stageV(nxt, n - 1); stageC(nxt, n - 1); }
    int i0 = n & 3;
    float tvx = i0 == 0 ? tvs[0] : i0 == 1 ? tvs[1] : i0 == 2 ? tvs[2] : tvs[3];
    float tvn = __shfl(tvx, ((n >> 2) << 4) + r);
    float csum = 0.f;
    #pragma unroll
    for (int s = 0; s < 4; ++s) {
      const float* cp = &c2t_s[cur][s * 32 + q * 8];
      float4 ca = *(const float4*)cp;
      float4 cb = *(const float4*)(cp + 4);
      float p0 = __expf(tvn * ca.x - M), p1 = __expf(tvn * ca.y - M);
      float p2 = __expf(tvn * ca.z - M), p3 = __expf(tvn * ca.w - M);
      float p4 = __expf(tvn * cb.x - M), p5 = __expf(tvn * cb.y - M);
      float p6 = __expf(tvn * cb.z - M), p7 = __expf(tvn * cb.w - M);
      csum += p0 + p1 + p2 + p3 + p4 + p5 + p6 + p7;
      h8 pa = { (_Float16)p0, (_Float16)p1, (_Float16)p2, (_Float16)p3,
                (_Float16)p4, (_Float16)p5, (_Float16)p6, (_Float16)p7 };
      #pragma unroll
      for (int t = 0; t < 4; ++t) {
        h8 vb = *(const h8*)&kv_s[cur][(t * 16 + r) * 128 + (((s * 4 + q) ^ r7) << 3)];
        oacc[t] = MFMA16(pa, vb, oacc[t]);
      }
    }
    csum += __shfl_xor(csum, 16);
    csum += __shfl_xor(csum, 32);
    den += csum;
  }

  // ---- masked-zero closed form + output ----
  int cnt = (L_ - 1) - rowA;
  den += e0 * (float)cnt;
  float e0r[4], dnr[4];
  #pragma unroll
  for (int i = 0; i < 4; ++i) {
    e0r[i] = __shfl(e0,  (q << 2) + i);
    dnr[i] = __shfl(den, (q << 2) + i);
  }
  #pragma unroll
  for (int t = 0; t < 4; ++t) {
    int d = t * 16 + r;
    float csf = CSUF[((size_t)bh * N_ + nq) * HD_ + d];
    #pragma unroll
    for (int i = 0; i < 4; ++i) {
      int row = l0 + w * 16 + q * 4 + i;
      float suffix = sacc[t][i] + csf;
      float o = (oacc[t][i] + e0r[i] * suffix) / dnr[i];
      AOh[((size_t)b2 * L_ + row) * D_ + h2 * HD_ + d] = (_Float16)o;
    }
  }
}

// ---------------------------------------------------------------------------
extern "C" void kernel_launch(void* const* d_in, const int* in_sizes, int n_in,
                              void* d_out, int out_size, void* d_ws, size_t ws_size,
                              hipStream_t stream)
{
  (void)in_sizes; (void)n_in; (void)out_size; (void)ws_size;
  const float* x     = (const float*)d_in[0];
  const float* w_qkv = (const float*)d_in[1];
  const float* b_qkv = (const float*)d_in[2];
  const float* w_o   = (const float*)d_in[3];
  const float* b_o   = (const float*)d_in[4];
  float* out = (float*)d_out;

  char* p = (char*)d_ws;
  _Float16* xh   = (_Float16*)p; p += (size_t)4194304 * 2;
  _Float16* wqT  = (_Float16*)p; p += (size_t)3145728 * 2;
  _Float16* woT  = (_Float16*)p; p += (size_t)1048576 * 2;
  _Float16* Qh   = (_Float16*)p; p += (size_t)4194304 * 2;
  _Float16* Kh   = (_Float16*)p; p += (size_t)4194304 * 2;
  _Float16* VT   = (_Float16*)p; p += (size_t)4194304 * 2;
  _Float16* AOh  = (_Float16*)p; p += (size_t)4194304 * 2;
  float*    C2T  = (float*)p;    p += (size_t)65536 * 4;
  float*    QP   = (float*)p;    p += (size_t)32768 * 4;
  float*    KP   = (float*)p;    p += (size_t)32768 * 4;
  float*    VCS  = (float*)p;    p += (size_t)32768 * 4;
  float*    CSUF = (float*)p;    p += (size_t)32768 * 4;
  float*    MXa  = (float*)p;    p += (size_t)512 * 4;
  float*    MNa  = (float*)p;    p += (size_t)512 * 4;

  cvtx_kernel<<<4096, 256, 0, stream>>>(x, xh);
  wt_kernel<<<dim3(96, 32), 256, 0, stream>>>(w_qkv, wqT, 3 * D_, D_);
  wt_kernel<<<dim3(32, 32), 256, 0, stream>>>(w_o, woT, D_, D_);
  gemm16_kernel<128><<<768, 256, 0, stream>>>(
      xh, wqT, b_qkv, Qh, Kh, VT, nullptr, QP, KP, VCS, D_, 0);
  csuf_kernel<<<B_ * H_, 64, 0, stream>>>(VCS, CSUF);
  c2t_kernel<<<B_ * H_ * N_, 128, 0, stream>>>(QP, Kh, C2T, MXa, MNa);
  attn3_kernel<<<1024, 256, 0, stream>>>(
      Qh, Kh, VT, C2T, MXa, MNa, CSUF, KP, AOh);
  gemm16_kernel<64><<<512, 256, 0, stream>>>(
      AOh, woT, b_o, nullptr, nullptr, nullptr, out, nullptr, nullptr, nullptr, D_, 1);
}

// Round 7
// 179.834 us; speedup vs baseline: 5.9649x; 1.0056x over previous
//
#include <hip/hip_runtime.h>
#include <math.h>

#define B_   2
#define L_   2048
#define D_   1024
#define H_   16
#define HD_  64
#define C_   128
#define N_   16
#define INV_SCALE 0.03125f   // 1/sqrt(1024)

typedef _Float16 h8 __attribute__((ext_vector_type(8)));
typedef _Float16 h4 __attribute__((ext_vector_type(4)));
typedef float    f4 __attribute__((ext_vector_type(4)));

#define MFMA16(a, b, c) __builtin_amdgcn_mfma_f32_16x16x32_f16((a), (b), (c), 0, 0, 0)

__device__ __forceinline__ void gl_lds16(const void* g, void* l) {
  __builtin_amdgcn_global_load_lds(
      (const __attribute__((address_space(1))) void*)g,
      (__attribute__((address_space(3))) void*)l, 16, 0, 0);
}

// ---------------------------------------------------------------------------
// Fused prep: blocks [0,4096) x fp32->fp16; [4096,7168) w_qkv transpose;
// [7168,8192) w_o transpose. All branches wave-uniform per block.
// ---------------------------------------------------------------------------
__global__ __launch_bounds__(256) void prep_kernel(
    const float* __restrict__ X, _Float16* __restrict__ Xh,
    const float* __restrict__ Wq, _Float16* __restrict__ WqT,
    const float* __restrict__ Wo, _Float16* __restrict__ WoT)
{
  __shared__ float ts[32][36];
  const int tid = threadIdx.x;
  const int id = blockIdx.x;
  if (id < 4096) {
    int i = id * 1024 + tid * 4;
    float4 v = *(const float4*)(X + i);
    h4 o = { (_Float16)v.x, (_Float16)v.y, (_Float16)v.z, (_Float16)v.w };
    *(h4*)(Xh + i) = o;
    return;
  }
  const float* W; _Float16* WT; int Nc, bx, by;
  if (id < 7168) {
    int idx = id - 4096;
    W = Wq; WT = WqT; Nc = 3072; bx = idx % 96; by = idx / 96;
  } else {
    int idx = id - 7168;
    W = Wo; WT = WoT; Nc = 1024; bx = idx & 31; by = idx >> 5;
  }
  const int n0 = bx * 32, k0 = by * 32;
  {
    int kr = tid >> 3, nc4 = (tid & 7) * 4;
    float4 v = *(const float4*)&W[(size_t)(k0 + kr) * Nc + n0 + nc4];
    ts[kr][nc4+0] = v.x; ts[kr][nc4+1] = v.y; ts[kr][nc4+2] = v.z; ts[kr][nc4+3] = v.w;
  }
  __syncthreads();
  {
    int nr = tid >> 3, kc4 = (tid & 7) * 4;
    h4 o = { (_Float16)ts[kc4+0][nr], (_Float16)ts[kc4+1][nr],
             (_Float16)ts[kc4+2][nr], (_Float16)ts[kc4+3][nr] };
    *(h4*)&WT[(size_t)(n0 + nr) * 1024 + k0 + kc4] = o;
  }
}

// ---------------------------------------------------------------------------
// fp16 MFMA GEMM, double-buffered global_load_lds staging, XCD-local tiling.
// MT=128 (QKV, mode 0): grid 768; XCD j owns n-tiles {3j..3j+2}. Scatter
//   epilogue -> Qh/Kh + VT + fused chunk pooling.
// MT=64 (out-proj, mode 1): grid 512; XCD j owns n-tile j.
// ---------------------------------------------------------------------------
template<int MT>
__global__ __launch_bounds__(256, 4) void gemm16_kernel(
    const _Float16* __restrict__ A, const _Float16* __restrict__ Bt,
    const float* __restrict__ bias,
    _Float16* __restrict__ Qh, _Float16* __restrict__ Kh, _Float16* __restrict__ VT,
    float* __restrict__ out,
    float* __restrict__ QP, float* __restrict__ KP, float* __restrict__ VCS,
    int Kd, int mode)
{
  constexpr int SM = MT / 32;
  __shared__ __align__(16) _Float16 As[2][MT * 32];
  __shared__ __align__(16) _Float16 Bs[2][4096];
  __shared__ float cred[2][128];
  const int tid = threadIdx.x;
  const int lane = tid & 63, w = tid >> 6;
  const int q = lane >> 4, r = lane & 15;
  const int mb = (w >> 1) * (MT / 2);
  const int nb = (w & 1) * 64;

  int m0, n0;
  {
    const int id = blockIdx.x;
    const int xcd = id & 7, slot = id >> 3;
    if constexpr (MT == 128) {
      n0 = (xcd * 3 + (slot % 3)) * 128;
      m0 = (slot / 3) * 128;
    } else {
      n0 = xcd * 128;
      m0 = slot * 64;
    }
  }

  const int Rr = tid >> 2;
  const int cd = (tid & 3) ^ ((Rr >> 1) & 3);
  const _Float16* Ag = A + (size_t)(m0 + Rr) * Kd + cd * 8;
  const _Float16* Bg = Bt + (size_t)(n0 + Rr) * Kd + cd * 8;
  const size_t rowStep = (size_t)64 * Kd;

  f4 acc[SM][4];
  #pragma unroll
  for (int s = 0; s < SM; ++s)
    #pragma unroll
    for (int t = 0; t < 4; ++t) acc[s][t] = (f4){0.f, 0.f, 0.f, 0.f};

  const int nIter = Kd >> 5;
  const int koff = (q ^ ((r >> 1) & 3)) << 3;

  auto stage = [&](int bf, int kt) {
    _Float16* Asl = &As[bf][w * 512];
    _Float16* Bsl = &Bs[bf][w * 512];
    gl_lds16(Ag + kt, Asl);
    if constexpr (MT == 128) gl_lds16(Ag + kt + rowStep, Asl + 2048);
    gl_lds16(Bg + kt, Bsl);
    gl_lds16(Bg + kt + rowStep, Bsl + 2048);
  };

  stage(0, 0);

  for (int it = 0; it < nIter; ++it) {
    __syncthreads();
    if (it + 1 < nIter) stage((it + 1) & 1, (it + 1) << 5);
    const _Float16* Ab = As[it & 1];
    const _Float16* Bb = Bs[it & 1];
    h8 af[SM], bf4[4];
    #pragma unroll
    for (int s = 0; s < SM; ++s)
      af[s] = *(const h8*)&Ab[(mb + s * 16 + r) * 32 + koff];
    #pragma unroll
    for (int t = 0; t < 4; ++t)
      bf4[t] = *(const h8*)&Bb[(nb + t * 16 + r) * 32 + koff];
    #pragma unroll
    for (int s = 0; s < SM; ++s)
      #pragma unroll
      for (int t = 0; t < 4; ++t)
        acc[s][t] = MFMA16(af[s], bf4[t], acc[s][t]);
  }

  if (mode == 0) {
    #pragma unroll
    for (int t = 0; t < 4; ++t) {
      int gn = n0 + nb + t * 16 + r;
      float bj = bias[gn];
      int which = gn >> 10, rem = gn & 1023;
      int h2 = rem >> 6, d2 = rem & 63;
      if (which < 2) {
        _Float16* dst = which == 0 ? Qh : Kh;
        #pragma unroll
        for (int s = 0; s < SM; ++s)
          #pragma unroll
          for (int i = 0; i < 4; ++i) {
            int gm = m0 + mb + s * 16 + q * 4 + i;
            int b2 = gm >> 11, l2 = gm & 2047;
            dst[(((size_t)(b2 * H_ + h2)) * L_ + l2) * HD_ + d2] =
                (_Float16)(acc[s][t][i] + bj);
          }
      } else {
        #pragma unroll
        for (int s = 0; s < SM; ++s) {
          int gm0 = m0 + mb + s * 16 + q * 4;
          int b2 = gm0 >> 11, l2 = gm0 & 2047;
          h4 hv = { (_Float16)(acc[s][t][0] + bj), (_Float16)(acc[s][t][1] + bj),
                    (_Float16)(acc[s][t][2] + bj), (_Float16)(acc[s][t][3] + bj) };
          *(h4*)&VT[((size_t)(b2 * H_ + h2) * HD_ + d2) * L_ + l2] = hv;
        }
      }
    }
    // -------- fused chunk pooling --------
    float colsum[4];
    #pragma unroll
    for (int t = 0; t < 4; ++t) {
      float s2 = 0.f;
      #pragma unroll
      for (int s = 0; s < SM; ++s)
        #pragma unroll
        for (int i = 0; i < 4; ++i) s2 += acc[s][t][i];
      s2 += __shfl_xor(s2, 16);
      s2 += __shfl_xor(s2, 32);
      colsum[t] = s2;
    }
    if (q == 0) {
      #pragma unroll
      for (int t = 0; t < 4; ++t)
        cred[w >> 1][nb + t * 16 + r] = colsum[t];
    }
    __syncthreads();
    if (tid < 128) {
      int jj = tid;
      float ssum = cred[0][jj] + cred[1][jj];
      int gn = n0 + jj;
      float bj = bias[gn];
      int which = gn >> 10, rem = gn & 1023;
      int h2 = rem >> 6, d2 = rem & 63;
      int b2 = m0 >> 11, nch = (m0 & 2047) >> 7;
      size_t o = (((size_t)(b2 * H_ + h2)) * N_ + nch) * HD_ + d2;
      if (which == 0)      QP[o] = ssum * (1.f / 128.f) + bj;
      else if (which == 1) KP[o] = ssum * (1.f / 128.f) + bj;
      else                 VCS[o] = ssum + 128.f * bj;
    }
  } else {
    #pragma unroll
    for (int t = 0; t < 4; ++t) {
      int gn = n0 + nb + t * 16 + r;
      float bj = bias[gn];
      #pragma unroll
      for (int s = 0; s < SM; ++s)
        #pragma unroll
        for (int i = 0; i < 4; ++i) {
          int gm = m0 + mb + s * 16 + q * 4 + i;
          out[(size_t)gm * 1024 + gn] = acc[s][t][i] + bj;
        }
    }
  }
}

// ---------------------------------------------------------------------------
// Fused pool2: blocks [0,512) c2t (+ per-chunk max/min); [512,544) csuf.
// ---------------------------------------------------------------------------
__global__ __launch_bounds__(128) void pool2_kernel(
    const float* __restrict__ QP, const _Float16* __restrict__ Kh,
    const float* __restrict__ VCS,
    float* __restrict__ C2T, float* __restrict__ C2TMX, float* __restrict__ C2TMN,
    float* __restrict__ CSUF)
{
  __shared__ float qp_s[64];
  __shared__ float red[4];
  if (blockIdx.x >= 512) {
    int bh = blockIdx.x - 512, d = threadIdx.x;
    if (d < 64) {
      float run = 0.f;
      for (int n = N_ - 1; n >= 0; --n) {
        size_t o = ((size_t)bh * N_ + n) * HD_ + d;
        CSUF[o] = run;
        run += VCS[o];
      }
    }
    return;
  }
  int bh = blockIdx.x >> 4, n = blockIdx.x & 15, tid = threadIdx.x;
  int w = tid >> 6, lane = tid & 63;
  if (tid < 64) qp_s[tid] = QP[((size_t)bh * N_ + n) * HD_ + tid];
  const _Float16* kr = Kh + (((size_t)bh * L_) + n * C_ + tid) * HD_;
  h8 kv[8];
  #pragma unroll
  for (int c8 = 0; c8 < 8; ++c8) kv[c8] = *(const h8*)(kr + c8 * 8);
  __syncthreads();
  float s = 0.f;
  #pragma unroll
  for (int c8 = 0; c8 < 8; ++c8)
    #pragma unroll
    for (int j = 0; j < 8; ++j)
      s = fmaf((float)kv[c8][j], qp_s[c8 * 8 + j], s);
  C2T[((size_t)bh * N_ + n) * C_ + tid] = s;
  float mx = s, mn = s;
  #pragma unroll
  for (int st = 1; st <= 32; st <<= 1) {
    mx = fmaxf(mx, __shfl_xor(mx, st));
    mn = fminf(mn, __shfl_xor(mn, st));
  }
  if (lane == 0) { red[w * 2] = mx; red[w * 2 + 1] = mn; }
  __syncthreads();
  if (tid == 0) {
    C2TMX[bh * N_ + n] = fmaxf(red[0], red[2]);
    C2TMN[bh * N_ + n] = fminf(red[1], red[3]);
  }
}

// ---------------------------------------------------------------------------
// One-pass MFMA attention, chunk-aligned 128-row tiles, 512 threads/8 waves.
// Diag chunk first -> final M known before accumulation. Staged V tiles
// serve all 128 rows (halved staging + barriers vs 64-row tiles).
// LDS: buf0 = K then P(waves 0..3); buf1 = P(waves 4..7) then V dbuf A;
//      buf2 = V(diag) then V dbuf B.
// ---------------------------------------------------------------------------
__global__ __launch_bounds__(512, 4) void attn4_kernel(
    const _Float16* __restrict__ Qh, const _Float16* __restrict__ Kh,
    const _Float16* __restrict__ VT,
    const float* __restrict__ C2T, const float* __restrict__ C2TMX,
    const float* __restrict__ C2TMN, const float* __restrict__ CSUF,
    const float* __restrict__ KP, _Float16* __restrict__ AOh)
{
  __shared__ __align__(16) _Float16 buf0[8192];
  __shared__ __align__(16) _Float16 buf1[8192];
  __shared__ __align__(16) _Float16 buf2[8192];
  __shared__ __align__(16) _Float16 kp_s[1024];
  __shared__ __align__(16) float c2t_s[2][128];

  const int tid = threadIdx.x;
  const int w = tid >> 6, lane = tid & 63;
  const int q = lane >> 4, r = lane & 15;
  const int r7 = r & 7;
  const int id = blockIdx.x;
  const int bh = ((id & 7) << 2) + ((id >> 3) & 3);   // XCD-aware
  const int nq = 15 - (id >> 5);                      // LPT: longest first
  const int l0 = nq * 128;
  const int rowA = l0 + w * 16 + r;
  const int pcw = w * 16 + r;
  const size_t bhL = (size_t)bh * L_;
  const int b2 = bh >> 4, h2 = bh & 15;

  auto stageV = [&](_Float16* buf, int n) {
    #pragma unroll
    for (int j2 = 0; j2 < 2; ++j2) {
      int f = j2 * 512 + tid;
      int d = f >> 4, p = f & 15;
      int c16 = p ^ (d & 7);
      gl_lds16(VT + ((size_t)bh * HD_ + d) * L_ + n * C_ + c16 * 8,
               buf + (size_t)(j2 * 512 + w * 64) * 8);
    }
  };
  auto stageK = [&](_Float16* buf, int n) {
    #pragma unroll
    for (int j2 = 0; j2 < 2; ++j2) {
      int f = j2 * 512 + tid;
      int c = f >> 3, p = f & 7;
      int ck = p ^ (c & 7);
      gl_lds16(Kh + (bhL + n * C_ + c) * HD_ + ck * 8,
               buf + (size_t)(j2 * 512 + w * 64) * 8);
    }
  };
  auto stageC = [&](int bf, int n) {
    if (tid < 32)
      gl_lds16(C2T + ((size_t)bh * N_ + n) * C_ + tid * 4, &c2t_s[bf][0]);
  };

  // ---- prologue ----
  if (tid < 256) {
    int n4 = tid >> 4, d4 = (tid & 15) * 4;
    float4 kpv = *(const float4*)&KP[((size_t)bh * N_ + n4) * HD_ + d4];
    int sd = ((((d4 >> 3) ^ (n4 & 7)) << 3) | (d4 & 7));
    h4 hv = { (_Float16)kpv.x, (_Float16)kpv.y, (_Float16)kpv.z, (_Float16)kpv.w };
    *(h4*)&kp_s[n4 * 64 + sd] = hv;
  }
  h8 qa0 = *(const h8*)(Qh + (bhL + rowA) * HD_ + q * 8);
  h8 qa1 = *(const h8*)(Qh + (bhL + rowA) * HD_ + 32 + q * 8);
  float mxL = C2TMX[bh * N_ + r];
  float mnL = C2TMN[bh * N_ + r];
  stageK(buf0, nq);
  stageV(buf2, nq);
  if (nq >= 1) stageC(0, nq - 1);
  __syncthreads();

  // ---- tval via MFMA: lane (q,r) reg i = tval[chunk q*4+i] for row rowA ----
  f4 tvacc = (f4){0.f, 0.f, 0.f, 0.f};
  {
    h8 kpa0 = *(const h8*)&kp_s[r * 64 + ((q ^ r7) << 3)];
    h8 kpa1 = *(const h8*)&kp_s[r * 64 + (((4 + q) ^ r7) << 3)];
    tvacc = MFMA16(kpa0, qa0, tvacc);
    tvacc = MFMA16(kpa1, qa1, tvacc);
  }
  float tvs[4];
  #pragma unroll
  for (int i = 0; i < 4; ++i) tvs[i] = tvacc[i] * INV_SCALE;

  // off-diag analytic row max
  float pm = -1e30f;
  #pragma unroll
  for (int i = 0; i < 4; ++i) {
    int n = q * 4 + i;
    float mx = __shfl(mxL, n);
    float mn = __shfl(mnL, n);
    float cm = fmaxf(tvs[i] * mx, tvs[i] * mn);
    pm = (n < nq) ? fmaxf(pm, cm) : pm;
  }
  pm = fmaxf(pm, __shfl_xor(pm, 16));
  pm = fmaxf(pm, __shfl_xor(pm, 32));

  // ---- diag chunk: QK^T over the full 128x128 chunk ----
  f4 sc[8];
  #pragma unroll
  for (int u = 0; u < 8; ++u) sc[u] = (f4){0.f, 0.f, 0.f, 0.f};
  #pragma unroll
  for (int u = 0; u < 8; ++u) {
    h8 kb0 = *(const h8*)&buf0[(u * 16 + r) * 64 + ((q ^ r7) << 3)];
    h8 kb1 = *(const h8*)&buf0[(u * 16 + r) * 64 + (((4 + q) ^ r7) << 3)];
    sc[u] = MFMA16(qa0, kb0, sc[u]);
    sc[u] = MFMA16(qa1, kb1, sc[u]);
  }

  float rm[4] = {-1e30f, -1e30f, -1e30f, -1e30f};
  #pragma unroll
  for (int u = 0; u < 8; ++u) {
    int lcol = u * 16 + r;
    #pragma unroll
    for (int i = 0; i < 4; ++i) {
      int lrow = w * 16 + q * 4 + i;
      float v = sc[u][i] * INV_SCALE;
      v = (lcol <= lrow) ? v : -1e30f;
      sc[u][i] = v;
      rm[i] = fmaxf(rm[i], v);
    }
  }
  #pragma unroll
  for (int i = 0; i < 4; ++i) {
    rm[i] = fmaxf(rm[i], __shfl_xor(rm[i], 1));
    rm[i] = fmaxf(rm[i], __shfl_xor(rm[i], 2));
    rm[i] = fmaxf(rm[i], __shfl_xor(rm[i], 4));
    rm[i] = fmaxf(rm[i], __shfl_xor(rm[i], 8));
  }
  const int srcl = (r >> 2) << 4;
  const int ri = r & 3;
  float t0 = __shfl(rm[0], srcl), t1 = __shfl(rm[1], srcl);
  float t2 = __shfl(rm[2], srcl), t3 = __shfl(rm[3], srcl);
  float myrm = ri == 0 ? t0 : ri == 1 ? t1 : ri == 2 ? t2 : t3;

  // ---- FINAL per-row max ----
  const float M = fmaxf(fmaxf(pm, myrm), 0.f);
  const float e0 = __expf(-M);
  float Mc[4];
  #pragma unroll
  for (int i = 0; i < 4; ++i) Mc[i] = __shfl(M, (q << 2) + i);

  float cs[4] = {0.f, 0.f, 0.f, 0.f};
  #pragma unroll
  for (int u = 0; u < 8; ++u)
    #pragma unroll
    for (int i = 0; i < 4; ++i) {
      float v = sc[u][i];
      float p = (v > -1e29f) ? __expf(v - Mc[i]) : 0.f;
      sc[u][i] = p;
      cs[i] += p;
    }
  #pragma unroll
  for (int i = 0; i < 4; ++i) {
    cs[i] += __shfl_xor(cs[i], 1);
    cs[i] += __shfl_xor(cs[i], 2);
    cs[i] += __shfl_xor(cs[i], 4);
    cs[i] += __shfl_xor(cs[i], 8);
  }
  float c0 = __shfl(cs[0], srcl), c1 = __shfl(cs[1], srcl);
  float c2 = __shfl(cs[2], srcl), c3 = __shfl(cs[3], srcl);
  float den = ri == 0 ? c0 : ri == 1 ? c1 : ri == 2 ? c2 : c3;

  __syncthreads();   // all K/kp reads done; V(diag) staged; P overlay safe

  // P per-wave slice: waves 0..3 in buf0, 4..7 in buf1 (own-wave r/w only)
  _Float16* pw = (w < 4) ? (buf0 + w * 2048) : (buf1 + (w - 4) * 2048);
  #pragma unroll
  for (int u = 0; u < 8; ++u)
    #pragma unroll
    for (int i = 0; i < 4; ++i) {
      int row = q * 4 + i, col = u * 16 + r;
      pw[row * 128 + ((((col >> 3) ^ (row & 7)) << 3) | (col & 7))] =
          (_Float16)sc[u][i];
    }

  f4 oacc[4], sacc[4];
  #pragma unroll
  for (int t = 0; t < 4; ++t) {
    oacc[t] = (f4){0.f, 0.f, 0.f, 0.f};
    sacc[t] = (f4){0.f, 0.f, 0.f, 0.f};
  }
  #pragma unroll
  for (int s = 0; s < 4; ++s) {
    h8 pa = *(const h8*)&pw[r * 128 + (((s * 4 + q) ^ r7) << 3)];
    h8 mk;
    #pragma unroll
    for (int j2 = 0; j2 < 8; ++j2)
      mk[j2] = (_Float16)((s * 32 + q * 8 + j2 > pcw) ? 1.f : 0.f);
    #pragma unroll
    for (int t = 0; t < 4; ++t) {
      h8 vb = *(const h8*)&buf2[(t * 16 + r) * 128 + (((s * 4 + q) ^ r7) << 3)];
      oacc[t] = MFMA16(pa, vb, oacc[t]);
      sacc[t] = MFMA16(mk, vb, sacc[t]);    // within-chunk suffix-V
    }
  }

  __syncthreads();   // P/V(diag) reads done
  if (nq >= 1) stageV(buf1, nq - 1);

  // ---- off-diagonal chunks, fixed M, no rescaling ----
  for (int n = nq - 1; n >= 0; --n) {
    const int k = nq - 1 - n;
    _Float16* curb = (k & 1) ? buf2 : buf1;
    __syncthreads();
    if (n >= 1) {
      stageV((k & 1) ? buf1 : buf2, n - 1);
      stageC((k + 1) & 1, n - 1);
    }
    int i0 = n & 3;
    float tvx = i0 == 0 ? tvs[0] : i0 == 1 ? tvs[1] : i0 == 2 ? tvs[2] : tvs[3];
    float tvn = __shfl(tvx, ((n >> 2) << 4) + r);
    float csum = 0.f;
    const float* c2p = c2t_s[k & 1];
    #pragma unroll
    for (int s = 0; s < 4; ++s) {
      const float* cp = &c2p[s * 32 + q * 8];
      float4 ca = *(const float4*)cp;
      float4 cb = *(const float4*)(cp + 4);
      float p0 = __expf(tvn * ca.x - M), p1 = __expf(tvn * ca.y - M);
      float p2 = __expf(tvn * ca.z - M), p3 = __expf(tvn * ca.w - M);
      float p4 = __expf(tvn * cb.x - M), p5 = __expf(tvn * cb.y - M);
      float p6 = __expf(tvn * cb.z - M), p7 = __expf(tvn * cb.w - M);
      csum += p0 + p1 + p2 + p3 + p4 + p5 + p6 + p7;
      h8 pa = { (_Float16)p0, (_Float16)p1, (_Float16)p2, (_Float16)p3,
                (_Float16)p4, (_Float16)p5, (_Float16)p6, (_Float16)p7 };
      #pragma unroll
      for (int t = 0; t < 4; ++t) {
        h8 vb = *(const h8*)&curb[(t * 16 + r) * 128 + (((s * 4 + q) ^ r7) << 3)];
        oacc[t] = MFMA16(pa, vb, oacc[t]);
      }
    }
    csum += __shfl_xor(csum, 16);
    csum += __shfl_xor(csum, 32);
    den += csum;
  }

  // ---- masked-zero closed form + output ----
  int cnt = (L_ - 1) - rowA;
  den += e0 * (float)cnt;
  float e0r[4], dnr[4];
  #pragma unroll
  for (int i = 0; i < 4; ++i) {
    e0r[i] = __shfl(e0,  (q << 2) + i);
    dnr[i] = __shfl(den, (q << 2) + i);
  }
  #pragma unroll
  for (int t = 0; t < 4; ++t) {
    int d = t * 16 + r;
    float csf = CSUF[((size_t)bh * N_ + nq) * HD_ + d];
    #pragma unroll
    for (int i = 0; i < 4; ++i) {
      int row = l0 + w * 16 + q * 4 + i;
      float suffix = sacc[t][i] + csf;
      float o = (oacc[t][i] + e0r[i] * suffix) / dnr[i];
      AOh[((size_t)b2 * L_ + row) * D_ + h2 * HD_ + d] = (_Float16)o;
    }
  }
}

// ---------------------------------------------------------------------------
extern "C" void kernel_launch(void* const* d_in, const int* in_sizes, int n_in,
                              void* d_out, int out_size, void* d_ws, size_t ws_size,
                              hipStream_t stream)
{
  (void)in_sizes; (void)n_in; (void)out_size; (void)ws_size;
  const float* x     = (const float*)d_in[0];
  const float* w_qkv = (const float*)d_in[1];
  const float* b_qkv = (const float*)d_in[2];
  const float* w_o   = (const float*)d_in[3];
  const float* b_o   = (const float*)d_in[4];
  float* out = (float*)d_out;

  char* p = (char*)d_ws;
  _Float16* xh   = (_Float16*)p; p += (size_t)4194304 * 2;
  _Float16* wqT  = (_Float16*)p; p += (size_t)3145728 * 2;
  _Float16* woT  = (_Float16*)p; p += (size_t)1048576 * 2;
  _Float16* Qh   = (_Float16*)p; p += (size_t)4194304 * 2;
  _Float16* Kh   = (_Float16*)p; p += (size_t)4194304 * 2;
  _Float16* VT   = (_Float16*)p; p += (size_t)4194304 * 2;
  _Float16* AOh  = (_Float16*)p; p += (size_t)4194304 * 2;
  float*    C2T  = (float*)p;    p += (size_t)65536 * 4;
  float*    QP   = (float*)p;    p += (size_t)32768 * 4;
  float*    KP   = (float*)p;    p += (size_t)32768 * 4;
  float*    VCS  = (float*)p;    p += (size_t)32768 * 4;
  float*    CSUF = (float*)p;    p += (size_t)32768 * 4;
  float*    MXa  = (float*)p;    p += (size_t)512 * 4;
  float*    MNa  = (float*)p;    p += (size_t)512 * 4;

  prep_kernel<<<8192, 256, 0, stream>>>(x, xh, w_qkv, wqT, w_o, woT);
  gemm16_kernel<128><<<768, 256, 0, stream>>>(
      xh, wqT, b_qkv, Qh, Kh, VT, nullptr, QP, KP, VCS, D_, 0);
  pool2_kernel<<<544, 128, 0, stream>>>(QP, Kh, VCS, C2T, MXa, MNa, CSUF);
  attn4_kernel<<<512, 512, 0, stream>>>(
      Qh, Kh, VT, C2T, MXa, MNa, CSUF, KP, AOh);
  gemm16_kernel<64><<<512, 256, 0, stream>>>(
      AOh, woT, b_o, nullptr, nullptr, nullptr, out, nullptr, nullptr, nullptr, D_, 1);
}